// Round 12
// baseline (3736.589 us; speedup 1.0000x reference)
//
#include <hip/hip_runtime.h>
#include <math.h>

// Sizes fixed by the problem
#define N_PTS   8192
#define BATCH   2
#define DIM     128
#define NOUT    2048
#define FPOFF   1048576   // 2048*2*256 floats of output 0
#define SLICE_MAX 800     // >= max span per fps_slice call (fin = 788!)

__device__ __forceinline__ float gelu_f(float v) {
  return 0.5f * v * (1.0f + erff(v * 0.70710678118654752440f));
}

// ---------------------------------------------------------------------------
// stable sorted top-8 insert, reference tie semantics (earlier insert wins)
// ---------------------------------------------------------------------------
__device__ __forceinline__ void knn_insert(float (&dist)[8], int (&idq)[8],
                                           float d2, int ci) {
  if (d2 < dist[7]) {
    float dd = d2;
#pragma unroll
    for (int j = 0; j < 8; ++j) {
      bool cc = dd < dist[j];
      float td = dist[j]; int ti = idq[j];
      dist[j] = cc ? dd : td; idq[j] = cc ? ci : ti;
      dd = cc ? td : dd; ci = cc ? ti : ci;
    }
  }
}

// ---------------------------------------------------------------------------
// FPS slice, 512 threads, 16 slots/thread.
// Winner COORDS published through LDS by the winner lane (k0==key test after
// the u64 butterfly — exactly one lane matches since the index part of the
// key is unique). No dependent global coord fetch per iteration.
// u64 key (d_bits<<32)|~gidx keeps exact first-index tie-break; block scan
// over 8 keys. State (mind, lp) persists in ws. Reference-exact:
// no-FMA fp32, (dx^2+dy^2)+dz^2, fminf.
// ---------------------------------------------------------------------------
__device__ __forceinline__ void fps_slice(
    const float* __restrict__ P, float* __restrict__ MWS, float* __restrict__ LPWS,
    float* __restrict__ FPWS, float* __restrict__ OUTFP,
    int b, int t0, int t1)
{
  __builtin_amdgcn_s_setprio(3);
  __shared__ unsigned long long wkeys[2][8];
  __shared__ float4 cvs[2][8];
  __shared__ float hist[SLICE_MAX * 3];
  const int tid = threadIdx.x;          // 0..511
  const int wv = tid >> 6;              // 0..7
  const float* __restrict__ Pb = P + (long)b * N_PTS * 3;
  float px[16], py[16], pz[16], mind[16];
#pragma unroll
  for (int s = 0; s < 16; ++s) {
    int i = s * 512 + tid;
    px[s] = Pb[i * 3 + 0];
    py[s] = Pb[i * 3 + 1];
    pz[s] = Pb[i * 3 + 2];
  }
  float lx, ly, lz;
  if (t0 == 0) {
#pragma unroll
    for (int s = 0; s < 16; ++s) mind[s] = INFINITY;
    lx = Pb[0]; ly = Pb[1]; lz = Pb[2];
    if (tid == 0) { hist[0] = lx; hist[1] = ly; hist[2] = lz; }
  } else {
#pragma unroll
    for (int s = 0; s < 16; ++s) mind[s] = MWS[b * N_PTS + s * 512 + tid];
    lx = LPWS[b * 4 + 0]; ly = LPWS[b * 4 + 1]; lz = LPWS[b * 4 + 2];
  }
  const int tstart = (t0 == 0) ? 1 : t0;
  for (int t = tstart; t < t1; ++t) {
    const int par = t & 1;
    float bv = -INFINITY; int bs = 0;
#pragma unroll
    for (int s = 0; s < 16; ++s) {
      float dx = __fsub_rn(px[s], lx);
      float dy = __fsub_rn(py[s], ly);
      float dz = __fsub_rn(pz[s], lz);
      float d = __fadd_rn(__fadd_rn(__fmul_rn(dx, dx), __fmul_rn(dy, dy)), __fmul_rn(dz, dz));
      float mm = fminf(mind[s], d);
      mind[s] = mm;
      bool c = mm > bv;                 // strict > : earliest slot (smallest gidx) wins
      bv = c ? mm : bv; bs = c ? s : bs;
    }
    unsigned long long key =
        ((unsigned long long)__float_as_uint(bv) << 32) |
        (unsigned int)~(unsigned int)(bs * 512 + tid);
    const unsigned long long k0 = key;
#pragma unroll
    for (int off = 1; off <= 32; off <<= 1) {
      unsigned long long o = __shfl_xor(key, off);
      key = (o > key) ? o : key;
    }
    if (k0 == key) {                    // exactly one lane per wave
      float ox = px[0], oy = py[0], oz = pz[0];
#pragma unroll
      for (int s2 = 1; s2 < 16; ++s2)
        if (bs == s2) { ox = px[s2]; oy = py[s2]; oz = pz[s2]; }
      wkeys[par][wv] = key;
      cvs[par][wv] = make_float4(ox, oy, oz, 0.f);
    }
    __syncthreads();
    unsigned long long wk = wkeys[par][0];
    int wu = 0;
#pragma unroll
    for (int u = 1; u < 8; ++u) {
      unsigned long long o = wkeys[par][u];
      bool bt = o > wk;                 // keys unique -> no tie handling needed
      wk = bt ? o : wk; wu = bt ? u : wu;
    }
    float4 wc = cvs[par][wu];           // same-address broadcast within wave
    lx = wc.x; ly = wc.y; lz = wc.z;
    if (tid == 0) {
      int h = (t - t0) * 3;
      hist[h + 0] = lx; hist[h + 1] = ly; hist[h + 2] = lz;
    }
    // next iteration writes the other parity buffer -> one barrier suffices
  }
  // persist state
#pragma unroll
  for (int s = 0; s < 16; ++s) MWS[b * N_PTS + s * 512 + tid] = mind[s];
  if (tid == 0) { LPWS[b * 4 + 0] = lx; LPWS[b * 4 + 1] = ly; LPWS[b * 4 + 2] = lz; }
  __syncthreads();
  const int cnt = (t1 - t0) * 3;
  const long base = ((long)b * NOUT + t0) * 3;
  for (int i = tid; i < cnt; i += 512) {
    float v2 = hist[i];
    FPWS[base + i] = v2;
    OUTFP[FPOFF + base + i] = v2;
  }
  __builtin_amdgcn_s_setprio(0);
}

// ---------------------------------------------------------------------------
// Partial KNN2 body: queries group qg (512 of the 4096 fp queries), candidate
// range r: [r*1024,(r+1)*1024). Batch-4 loop, LDS staging. Output partial
// top-8 at [((b*NOUT+m)*8 + r)*8 + j].
// ---------------------------------------------------------------------------
__device__ __forceinline__ void knn2p_body(
    const float* __restrict__ Q, const float* __restrict__ Pp,
    float* __restrict__ PD, int* __restrict__ PI, int qg, int r)
{
  __shared__ float4 shp[512];
  const int b = qg >> 2;                 // 4 groups per batch
  const int m = (qg & 3) * 512 + threadIdx.x;
  const float qx = Q[(b * NOUT + m) * 3 + 0];
  const float qy = Q[(b * NOUT + m) * 3 + 1];
  const float qz = Q[(b * NOUT + m) * 3 + 2];
  const float sqq = __fadd_rn(__fadd_rn(__fmul_rn(qx, qx), __fmul_rn(qy, qy)), __fmul_rn(qz, qz));
  float dist[8]; int idq[8];
#pragma unroll
  for (int j = 0; j < 8; ++j) { dist[j] = INFINITY; idq[j] = 0; }
  const int cb = r * 1024;
  for (int tt = 0; tt < 1024; tt += 512) {
    __syncthreads();
    {
      int l = threadIdx.x;
      float x = Pp[(b * N_PTS + cb + tt + l) * 3 + 0];
      float y = Pp[(b * N_PTS + cb + tt + l) * 3 + 1];
      float z = Pp[(b * N_PTS + cb + tt + l) * 3 + 2];
      float s = __fadd_rn(__fadd_rn(__fmul_rn(x, x), __fmul_rn(y, y)), __fmul_rn(z, z));
      shp[l] = make_float4(x, y, z, s);
    }
    __syncthreads();
    for (int c = 0; c < 512; c += 4) {
      float4 p0 = shp[c + 0];
      float4 p1 = shp[c + 1];
      float4 p2 = shp[c + 2];
      float4 p3 = shp[c + 3];
      float d0 = __fsub_rn(__fadd_rn(sqq, p0.w), __fmul_rn(2.0f,
                 __fadd_rn(__fadd_rn(__fmul_rn(qx, p0.x), __fmul_rn(qy, p0.y)), __fmul_rn(qz, p0.z))));
      float d1 = __fsub_rn(__fadd_rn(sqq, p1.w), __fmul_rn(2.0f,
                 __fadd_rn(__fadd_rn(__fmul_rn(qx, p1.x), __fmul_rn(qy, p1.y)), __fmul_rn(qz, p1.z))));
      float d2 = __fsub_rn(__fadd_rn(sqq, p2.w), __fmul_rn(2.0f,
                 __fadd_rn(__fadd_rn(__fmul_rn(qx, p2.x), __fmul_rn(qy, p2.y)), __fmul_rn(qz, p2.z))));
      float d3 = __fsub_rn(__fadd_rn(sqq, p3.w), __fmul_rn(2.0f,
                 __fadd_rn(__fadd_rn(__fmul_rn(qx, p3.x), __fmul_rn(qy, p3.y)), __fmul_rn(qz, p3.z))));
      float mn = fminf(fminf(d0, d1), fminf(d2, d3));
      if (mn < dist[7]) {
        knn_insert(dist, idq, d0, cb + tt + c + 0);
        knn_insert(dist, idq, d1, cb + tt + c + 1);
        knn_insert(dist, idq, d2, cb + tt + c + 2);
        knn_insert(dist, idq, d3, cb + tt + c + 3);
      }
    }
  }
  const long ob = ((long)(b * NOUT + m) * 8 + r) * 8;
#pragma unroll
  for (int j = 0; j < 8; ++j) { PD[ob + j] = dist[j]; PI[ob + j] = idq[j]; }
}

// fps finisher; also hosts knn2p for queries < 1024 per batch (qg in
// {0,1,4,5}), which are complete before this launch (chain covered >= 1260).
__global__ __launch_bounds__(512) void fps_fin(
    const float* __restrict__ P, float* __restrict__ MWS, float* __restrict__ LPWS,
    float* __restrict__ FPWS, float* __restrict__ OUTFP,
    float* __restrict__ PD2, int* __restrict__ PI2, int t0, int t1)
{
  if ((int)blockIdx.x < 2) {
    fps_slice(P, MWS, LPWS, FPWS, OUTFP, (int)blockIdx.x, t0, t1);
    return;
  }
  const int wid = (int)blockIdx.x - 2;   // 0..31
  const int qidx = wid >> 3;             // 0..3 -> qg in {0,1,4,5}
  const int r = wid & 7;
  const int qg = (qidx & 1) | ((qidx >> 1) << 2);   // 0,1,4,5
  knn2p_body(FPWS, P, PD2, PI2, qg, r);
}

// remaining knn2 partials (queries 1024..2047 per batch): qg in {2,3,6,7}
__global__ __launch_bounds__(512) void knn2pb_k(
    const float* __restrict__ Q, const float* __restrict__ Pp,
    float* __restrict__ PD, int* __restrict__ PI)
{
  const int qidx = (int)blockIdx.x >> 3;   // 0..3
  const int r = (int)blockIdx.x & 7;
  const int qg = 2 + (qidx & 1) + ((qidx >> 1) << 2);  // 2,3,6,7
  knn2p_body(Q, Pp, PD, PI, qg, r);
}

// ---------------------------------------------------------------------------
// Fused-pair fp32 GEMM host (512 threads = 2 teams x 256); blocks 0,1 = fps.
// ---------------------------------------------------------------------------
__global__ __launch_bounds__(512) void gemm2_k(
    const float* __restrict__ A, const float* __restrict__ W,
    const float* __restrict__ bias, float* __restrict__ OUT,
    const float* __restrict__ resid,
    int nbx, int N, int K, int a_mode, int o_mode, int act,
    const float* __restrict__ P, float* __restrict__ MWS, float* __restrict__ LPWS,
    float* __restrict__ FPWS, float* __restrict__ OUTFP, int t0, int t1)
{
  if ((int)blockIdx.x < 2) {
    fps_slice(P, MWS, LPWS, FPWS, OUTFP, (int)blockIdx.x, t0, t1);
    return;
  }
  const int wid = (int)blockIdx.x - 2;
  __shared__ float As[2][16][132];
  __shared__ float Ws2[2][16][132];
  const int team = threadIdx.x >> 8;
  const int tid = threadIdx.x & 255;
  const int tx = tid & 15, ty = tid >> 4;
  const int bx = wid % nbx;
  const int byy = (wid / nbx) * 2 + team;
  float acc[8][8];
#pragma unroll
  for (int i = 0; i < 8; ++i)
#pragma unroll
    for (int j = 0; j < 8; ++j) acc[i][j] = 0.f;

  for (int k0 = 0; k0 < K; k0 += 16) {
#pragma unroll
    for (int rep = 0; rep < 2; ++rep) {
      int qq = tid + rep * 256;          // 0..511
      int m = qq >> 2, kq = qq & 3;      // A: 128 rows x 16k as float4
      int r = byy * 128 + m;
      int arow = (a_mode == 1) ? ((r & 8191) * 2 + (r >> 13)) : r;
      const float4 av = *(const float4*)(A + (long)arow * K + k0 + kq * 4);
      As[team][kq * 4 + 0][m] = av.x; As[team][kq * 4 + 1][m] = av.y;
      As[team][kq * 4 + 2][m] = av.z; As[team][kq * 4 + 3][m] = av.w;
      int kw = qq >> 5, nq = qq & 31;    // W: 16k x 128 cols
      const float4 wv = *(const float4*)(W + (long)(k0 + kw) * N + bx * 128 + nq * 4);
      *(float4*)&Ws2[team][kw][nq * 4] = wv;
    }
    __syncthreads();
#pragma unroll
    for (int kk = 0; kk < 16; ++kk) {
      float4 a0 = *(const float4*)&As[team][kk][ty * 8];
      float4 a1 = *(const float4*)&As[team][kk][ty * 8 + 4];
      float4 w0 = *(const float4*)&Ws2[team][kk][tx * 4];
      float4 w1 = *(const float4*)&Ws2[team][kk][64 + tx * 4];
      float am[8] = {a0.x, a0.y, a0.z, a0.w, a1.x, a1.y, a1.z, a1.w};
      float wn[8] = {w0.x, w0.y, w0.z, w0.w, w1.x, w1.y, w1.z, w1.w};
#pragma unroll
      for (int i = 0; i < 8; ++i)
#pragma unroll
        for (int j = 0; j < 8; ++j) acc[i][j] += am[i] * wn[j];
    }
    __syncthreads();
  }
  const int c0 = bx * 128 + tx * 4;
  const int c1 = c0 + 64;
  float4 ba = *(const float4*)(bias + c0);
  float4 bb = *(const float4*)(bias + c1);
#pragma unroll
  for (int i = 0; i < 8; ++i) {
    int r = byy * 128 + ty * 8 + i;
    int orow = (o_mode == 1) ? ((r & 8191) * 2 + (r >> 13))
             : (o_mode == 2) ? ((r & 1) * 8192 + (r >> 1)) : r;
    float o[8] = {acc[i][0] + ba.x, acc[i][1] + ba.y, acc[i][2] + ba.z, acc[i][3] + ba.w,
                  acc[i][4] + bb.x, acc[i][5] + bb.y, acc[i][6] + bb.z, acc[i][7] + bb.w};
    if (act == 1) {
#pragma unroll
      for (int j = 0; j < 8; ++j) o[j] = gelu_f(o[j]);
    }
    if (resid) {
      float4 r0 = *(const float4*)(resid + (long)orow * N + c0);
      float4 r1 = *(const float4*)(resid + (long)orow * N + c1);
      o[0] += r0.x; o[1] += r0.y; o[2] += r0.z; o[3] += r0.w;
      o[4] += r1.x; o[5] += r1.y; o[6] += r1.z; o[7] += r1.w;
    }
    *(float4*)(OUT + (long)orow * N + c0) = make_float4(o[0], o[1], o[2], o[3]);
    *(float4*)(OUT + (long)orow * N + c1) = make_float4(o[4], o[5], o[6], o[7]);
  }
}

// ---------------------------------------------------------------------------
// Partial KNN1 host (512 thr); blocks 0,1 = fps. 128 work blocks:
// wid = bid-2; qg = wid>>2 (32 groups of 512 queries); r = wid&3 (cand range).
// ---------------------------------------------------------------------------
__global__ __launch_bounds__(512) void knn1p_k(
    const float* __restrict__ Pp, float* __restrict__ PD, int* __restrict__ PI,
    const float* __restrict__ P, float* __restrict__ MWS, float* __restrict__ LPWS,
    float* __restrict__ FPWS, float* __restrict__ OUTFP, int t0, int t1)
{
  if ((int)blockIdx.x < 2) {
    fps_slice(P, MWS, LPWS, FPWS, OUTFP, (int)blockIdx.x, t0, t1);
    return;
  }
  const int wid = (int)blockIdx.x - 2;   // 0..127
  const int qg = wid >> 2;               // 0..31
  const int r = wid & 3;
  const int b = qg >> 4;                 // 16 groups per batch
  const int m = (qg & 15) * 512 + threadIdx.x;
  __shared__ float4 shp[512];
  const float qx = Pp[(b * N_PTS + m) * 3 + 0];
  const float qy = Pp[(b * N_PTS + m) * 3 + 1];
  const float qz = Pp[(b * N_PTS + m) * 3 + 2];
  const float sqq = __fadd_rn(__fadd_rn(__fmul_rn(qx, qx), __fmul_rn(qy, qy)), __fmul_rn(qz, qz));
  float dist[8]; int idq[8];
#pragma unroll
  for (int j = 0; j < 8; ++j) { dist[j] = INFINITY; idq[j] = 0; }
  const int cb = r * 2048;
  for (int tt = 0; tt < 2048; tt += 512) {
    __syncthreads();
    {
      int l = threadIdx.x;
      float x = Pp[(b * N_PTS + cb + tt + l) * 3 + 0];
      float y = Pp[(b * N_PTS + cb + tt + l) * 3 + 1];
      float z = Pp[(b * N_PTS + cb + tt + l) * 3 + 2];
      float s = __fadd_rn(__fadd_rn(__fmul_rn(x, x), __fmul_rn(y, y)), __fmul_rn(z, z));
      shp[l] = make_float4(x, y, z, s);
    }
    __syncthreads();
    for (int c = 0; c < 512; c += 4) {
      float4 p0 = shp[c + 0];
      float4 p1 = shp[c + 1];
      float4 p2 = shp[c + 2];
      float4 p3 = shp[c + 3];
      float d0 = __fsub_rn(__fadd_rn(sqq, p0.w), __fmul_rn(2.0f,
                 __fadd_rn(__fadd_rn(__fmul_rn(qx, p0.x), __fmul_rn(qy, p0.y)), __fmul_rn(qz, p0.z))));
      float d1 = __fsub_rn(__fadd_rn(sqq, p1.w), __fmul_rn(2.0f,
                 __fadd_rn(__fadd_rn(__fmul_rn(qx, p1.x), __fmul_rn(qy, p1.y)), __fmul_rn(qz, p1.z))));
      float d2 = __fsub_rn(__fadd_rn(sqq, p2.w), __fmul_rn(2.0f,
                 __fadd_rn(__fadd_rn(__fmul_rn(qx, p2.x), __fmul_rn(qy, p2.y)), __fmul_rn(qz, p2.z))));
      float d3 = __fsub_rn(__fadd_rn(sqq, p3.w), __fmul_rn(2.0f,
                 __fadd_rn(__fadd_rn(__fmul_rn(qx, p3.x), __fmul_rn(qy, p3.y)), __fmul_rn(qz, p3.z))));
      float mn = fminf(fminf(d0, d1), fminf(d2, d3));
      if (mn < dist[7]) {
        knn_insert(dist, idq, d0, cb + tt + c + 0);
        knn_insert(dist, idq, d1, cb + tt + c + 1);
        knn_insert(dist, idq, d2, cb + tt + c + 2);
        knn_insert(dist, idq, d3, cb + tt + c + 3);
      }
    }
  }
  const long ob = ((long)(b * N_PTS + m) * 4 + r) * 8;
#pragma unroll
  for (int j = 0; j < 8; ++j) { PD[ob + j] = dist[j]; PI[ob + j] = idq[j]; }
}

// ---------------------------------------------------------------------------
// Fused neighbor attention, 512-thr host; blocks 0,1 = fps.
// Merges the 4 knn1 partial lists inline per wave (ranges in ascending index
// order -> identical tie semantics to a monolithic scan).
// ---------------------------------------------------------------------------
__global__ __launch_bounds__(512) void attn_k(
    const float* __restrict__ Qb, const float* __restrict__ Kb, const float* __restrict__ Vb,
    const float* __restrict__ Pp,
    const float* __restrict__ PD1, const int* __restrict__ PI1,
    const float* __restrict__ Wpe1, const float* __restrict__ bpe1,
    const float* __restrict__ Wpe2, const float* __restrict__ bpe2,
    const float* __restrict__ Wg, const float* __restrict__ bg,
    float* __restrict__ RES,
    const float* __restrict__ P, float* __restrict__ MWS, float* __restrict__ LPWS,
    float* __restrict__ FPWS, float* __restrict__ OUTFP, int t0, int t1)
{
  if ((int)blockIdx.x < 2) {
    fps_slice(P, MWS, LPWS, FPWS, OUTFP, (int)blockIdx.x, t0, t1);
    return;
  }
  __shared__ float sbuf[8][1024];
  const int tid = threadIdx.x;
  const int w = tid >> 6, lane = tid & 63;
  const int g = ((int)blockIdx.x - 2) * 8 + w;   // 0..16383 : b*8192+n
  const int b = g >> 13, n = g & 8191;
  const int j0 = lane * 2;
  float* sb = sbuf[w];
  const float2 qv = *(const float2*)(Qb + (long)g * 128 + j0);
  // inline merge of 4 partial top-8 lists (wave-uniform, broadcast loads)
  float mdist[8]; int nb[8];
#pragma unroll
  for (int j = 0; j < 8; ++j) { mdist[j] = INFINITY; nb[j] = 0; }
#pragma unroll
  for (int r = 0; r < 4; ++r) {
    const long ob = ((long)g * 4 + r) * 8;
#pragma unroll
    for (int j = 0; j < 8; ++j) knn_insert(mdist, nb, PD1[ob + j], PI1[ob + j]);
  }
  const float p0 = Pp[(b * N_PTS + n) * 3 + 0];
  const float p1 = Pp[(b * N_PTS + n) * 3 + 1];
  const float p2 = Pp[(b * N_PTS + n) * 3 + 2];
  // phase A: h1 = gelu(rel @ Wpe1 + bpe1) -> LDS
  const float2 w1a = *(const float2*)(Wpe1 + j0);
  const float2 w1b = *(const float2*)(Wpe1 + 128 + j0);
  const float2 w1c = *(const float2*)(Wpe1 + 256 + j0);
  const float2 b1 = *(const float2*)(bpe1 + j0);
#pragma unroll
  for (int kk = 0; kk < 8; ++kk) {
    const float* pn = Pp + (long)(b * N_PTS + nb[kk]) * 3;
    float r0 = p0 - pn[0], r1 = p1 - pn[1], r2 = p2 - pn[2];
    float h0 = r0 * w1a.x + r1 * w1b.x + r2 * w1c.x + b1.x;
    float h1 = r0 * w1a.y + r1 * w1b.y + r2 * w1c.y + b1.y;
    sb[kk * 128 + j0]     = gelu_f(h0);
    sb[kk * 128 + j0 + 1] = gelu_f(h1);
  }
  __syncthreads();
  // phase B: pe = h1 @ Wpe2
  float2 pe[8];
#pragma unroll
  for (int kk = 0; kk < 8; ++kk) pe[kk] = make_float2(0.f, 0.f);
  for (int i = 0; i < 128; i += 2) {
    float2 wa = *(const float2*)(Wpe2 + (long)i * 128 + j0);
    float2 wb = *(const float2*)(Wpe2 + (long)(i + 1) * 128 + j0);
#pragma unroll
    for (int kk = 0; kk < 8; ++kk) {
      float2 hh = *(const float2*)&sb[kk * 128 + i];
      pe[kk].x += hh.x * wa.x + hh.y * wb.x;
      pe[kk].y += hh.x * wa.y + hh.y * wb.y;
    }
  }
  const float2 b2v = *(const float2*)(bpe2 + j0);
  __syncthreads();
  // t = q - k_nb + pe  -> LDS (reuse buffer)
#pragma unroll
  for (int kk = 0; kk < 8; ++kk) {
    pe[kk].x += b2v.x; pe[kk].y += b2v.y;
    const float2 kv = *(const float2*)(Kb + (long)(b * N_PTS + nb[kk]) * 128 + j0);
    sb[kk * 128 + j0]     = qv.x - kv.x + pe[kk].x;
    sb[kk * 128 + j0 + 1] = qv.y - kv.y + pe[kk].y;
  }
  __syncthreads();
  // phase C: a = t @ Wg
  float2 av[8];
#pragma unroll
  for (int kk = 0; kk < 8; ++kk) av[kk] = make_float2(0.f, 0.f);
  for (int i = 0; i < 128; i += 2) {
    float2 wa = *(const float2*)(Wg + (long)i * 128 + j0);
    float2 wb = *(const float2*)(Wg + (long)(i + 1) * 128 + j0);
#pragma unroll
    for (int kk = 0; kk < 8; ++kk) {
      float2 tt = *(const float2*)&sb[kk * 128 + i];
      av[kk].x += tt.x * wa.x + tt.y * wb.x;
      av[kk].y += tt.x * wa.y + tt.y * wb.y;
    }
  }
  const float2 bgv = *(const float2*)(bg + j0);
  float2 resv = make_float2(0.f, 0.f);
  const float sd = 11.313708498984761f;   // sqrt(128)
#pragma unroll
  for (int kk = 0; kk < 8; ++kk) {
    float l0 = (av[kk].x + bgv.x) / sd;
    float l1 = (av[kk].y + bgv.y) / sd;
    float mx = fmaxf(l0, l1);
#pragma unroll
    for (int off = 32; off >= 1; off >>= 1) mx = fmaxf(mx, __shfl_xor(mx, off));
    float e0 = expf(l0 - mx), e1 = expf(l1 - mx);
    float sm = e0 + e1;
#pragma unroll
    for (int off = 32; off >= 1; off >>= 1) sm += __shfl_xor(sm, off);
    const float2 vv = *(const float2*)(Vb + (long)(b * N_PTS + nb[kk]) * 128 + j0);
    resv.x += (e0 / sm) * (vv.x + pe[kk].x);
    resv.y += (e1 / sm) * (vv.y + pe[kk].y);
  }
  *(float2*)(RES + (long)g * 128 + j0) = resv;
}

// ---------------------------------------------------------------------------
// RMSNorm in-place, 512-thr host (8 rows/block); blocks 0,1 = fps.
// ---------------------------------------------------------------------------
__global__ __launch_bounds__(512) void rms_k(
    float* __restrict__ X, const float* __restrict__ scale,
    const float* __restrict__ P, float* __restrict__ MWS, float* __restrict__ LPWS,
    float* __restrict__ FPWS, float* __restrict__ OUTFP, int t0, int t1)
{
  if ((int)blockIdx.x < 2) {
    fps_slice(P, MWS, LPWS, FPWS, OUTFP, (int)blockIdx.x, t0, t1);
    return;
  }
  const int tid = threadIdx.x;
  const int w = tid >> 6, lane = tid & 63;
  const long row = (long)((int)blockIdx.x - 2) * 8 + w;
  float2 xv = *(float2*)(X + row * 128 + lane * 2);
  float ss = xv.x * xv.x + xv.y * xv.y;
#pragma unroll
  for (int off = 32; off >= 1; off >>= 1) ss += __shfl_xor(ss, off);
  const float rms = sqrtf(ss) / 11.313708498984761f;
  const float den = rms + 1e-8f;
  const float2 sc = *(const float2*)(scale + lane * 2);
  float2 o;
  o.x = sc.x * (xv.x / den);
  o.y = sc.y * (xv.y / den);
  *(float2*)(X + row * 128 + lane * 2) = o;
}

// ---------------------------------------------------------------------------
// PointPool with inline merge of the 8 knn2 partial lists per output point.
// ---------------------------------------------------------------------------
__global__ __launch_bounds__(256) void pool_k(
    const float* __restrict__ X3, const float* __restrict__ FPWS,
    const float* __restrict__ PD2, const int* __restrict__ PI2,
    const float* __restrict__ Wp, float* __restrict__ OUT)
{
  __shared__ float sh[8][256];
  __shared__ float fp3[3];
  const int bm = blockIdx.x;           // b*2048 + m
  const int b = bm >> 11;
  const int m = bm & 2047;
  const int tid = threadIdx.x;
  // inline merge (block-uniform, broadcast loads)
  float mdist[8]; int kidx[8];
#pragma unroll
  for (int j = 0; j < 8; ++j) { mdist[j] = INFINITY; kidx[j] = 0; }
#pragma unroll
  for (int r = 0; r < 8; ++r) {
    const long ob = ((long)bm * 8 + r) * 8;
#pragma unroll
    for (int j = 0; j < 8; ++j) knn_insert(mdist, kidx, PD2[ob + j], PI2[ob + j]);
  }
#pragma unroll
  for (int kk = 0; kk < 8; ++kk) {
    sh[kk][tid] = X3[(long)(b * N_PTS + kidx[kk]) * 256 + tid];
  }
  if (tid < 3) fp3[tid] = FPWS[bm * 3 + tid];
  __syncthreads();
  float base = fp3[0] * Wp[tid] + fp3[1] * Wp[256 + tid] + fp3[2] * Wp[512 + tid];
  float acc[8];
#pragma unroll
  for (int kk = 0; kk < 8; ++kk) acc[kk] = base;
  for (int i = 0; i < 256; i += 2) {
    float w0 = Wp[(3 + i) * 256 + tid];
    float w1 = Wp[(4 + i) * 256 + tid];
#pragma unroll
    for (int kk = 0; kk < 8; ++kk) {
      float2 hh = *(const float2*)&sh[kk][i];
      acc[kk] += hh.x * w0 + hh.y * w1;
    }
  }
  float mx = -INFINITY;
#pragma unroll
  for (int kk = 0; kk < 8; ++kk) {
    float a = acc[kk];
    a = (a >= 0.f) ? a : 0.01f * a;      // LeakyReLU(0.01)
    mx = fmaxf(mx, a);
  }
  OUT[(long)(m * 2 + b) * 256 + tid] = mx;   // (n_out, B, 2D)
}

// ---------------------------------------------------------------------------
extern "C" void kernel_launch(void* const* d_in, const int* in_sizes, int n_in,
                              void* d_out, int out_size, void* d_ws, size_t ws_size,
                              hipStream_t stream)
{
  (void)in_sizes; (void)n_in; (void)out_size; (void)ws_size;
  const float* x    = (const float*)d_in[0];
  const float* ppos = (const float*)d_in[1];
  const float* Wq = (const float*)d_in[2];   const float* bq = (const float*)d_in[3];
  const float* Wk = (const float*)d_in[4];   const float* bk = (const float*)d_in[5];
  const float* Wv = (const float*)d_in[6];   const float* bv = (const float*)d_in[7];
  const float* Wpe1 = (const float*)d_in[8]; const float* bpe1 = (const float*)d_in[9];
  const float* Wpe2 = (const float*)d_in[10];const float* bpe2 = (const float*)d_in[11];
  const float* Wg = (const float*)d_in[12];  const float* bg = (const float*)d_in[13];
  const float* Wo = (const float*)d_in[14];  const float* bo = (const float*)d_in[15];
  const float* scale = (const float*)d_in[16];
  const float* Wf1 = (const float*)d_in[17]; const float* bf1 = (const float*)d_in[18];
  const float* Wf2 = (const float*)d_in[19]; const float* bf2 = (const float*)d_in[20];
  const float* Wpool = (const float*)d_in[21];
  float* out = (float*)d_out;
  char* ws = (char*)d_ws;

  // workspace layout (peak ~49 MB, aliased):
  float* qb   = (float*)(ws);                                   // 8 MB (B,N,128)
  float* kb   = (float*)(ws + (size_t)8 * 1024 * 1024);         // 8 MB
  float* vb   = (float*)(ws + (size_t)16 * 1024 * 1024);        // 8 MB
  float* res  = (float*)(ws + (size_t)24 * 1024 * 1024);        // 8 MB
  float* x2   = (float*)(ws + (size_t)32 * 1024 * 1024);        // 8 MB (N,B,128)
  float* hbuf = (float*)(ws);                                   // 32 MB, aliases qb..res
  float* x3   = (float*)(ws + (size_t)32 * 1024 * 1024);        // 16 MB (B,N,256), aliases x2
  // knn1 partials in the x2 slot (x2 is written by Wo AFTER attn consumed them)
  float* PD1  = (float*)(ws + (size_t)32 * 1024 * 1024);        // 2 MB
  int*   PI1  = (int*)  (ws + (size_t)34 * 1024 * 1024);        // 2 MB
  // knn2 partials in the hbuf slot (dead after ffn2; written in fin and later)
  float* PD2  = (float*)(ws);                                   // 1 MB
  int*   PI2  = (int*)  (ws + (size_t)1 * 1024 * 1024);         // 1 MB
  char*  tail = ws + (size_t)48 * 1024 * 1024;
  float* fpws = (float*)(tail);                       // 64 KB slot (48 used)
  float* MWS  = (float*)(tail + 65536);               // 64 KB fps mind state
  float* LPWS = (float*)(tail + 131072);              // 4 KB fps lp state

  // fps spans (sum = 2048): qkv 3x110, knn1p 120, attn 360, Wo 110, rms 40,
  // ffn1 170, ffn2 130, fin 788 (SLICE_MAX=800 covers it).
  gemm2_k<<<dim3(66), dim3(512), 0, stream>>>(x, Wq, bq, qb, nullptr, 1, 128, 128, 1, 0, 0,
                                              ppos, MWS, LPWS, fpws, out, 0, 110);
  gemm2_k<<<dim3(66), dim3(512), 0, stream>>>(x, Wk, bk, kb, nullptr, 1, 128, 128, 1, 0, 0,
                                              ppos, MWS, LPWS, fpws, out, 110, 220);
  gemm2_k<<<dim3(66), dim3(512), 0, stream>>>(x, Wv, bv, vb, nullptr, 1, 128, 128, 1, 0, 0,
                                              ppos, MWS, LPWS, fpws, out, 220, 330);
  knn1p_k<<<dim3(130), dim3(512), 0, stream>>>(ppos, PD1, PI1,
                                               ppos, MWS, LPWS, fpws, out, 330, 450);
  attn_k<<<dim3(2050), dim3(512), 0, stream>>>(qb, kb, vb, ppos, PD1, PI1,
                                               Wpe1, bpe1, Wpe2, bpe2, Wg, bg, res,
                                               ppos, MWS, LPWS, fpws, out, 450, 810);
  gemm2_k<<<dim3(66), dim3(512), 0, stream>>>(res, Wo, bo, x2, x, 1, 128, 128, 0, 1, 0,
                                              ppos, MWS, LPWS, fpws, out, 810, 920);
  rms_k<<<dim3(2050), dim3(512), 0, stream>>>(x2, scale,
                                              ppos, MWS, LPWS, fpws, out, 920, 960);
  gemm2_k<<<dim3(258), dim3(512), 0, stream>>>(x2, Wf1, bf1, hbuf, nullptr, 4, 512, 128, 0, 0, 1,
                                               ppos, MWS, LPWS, fpws, out, 960, 1130);
  gemm2_k<<<dim3(130), dim3(512), 0, stream>>>(hbuf, Wf2, bf2, x3, nullptr, 2, 256, 512, 0, 2, 0,
                                               ppos, MWS, LPWS, fpws, out, 1130, 1260);
  // fin: fps 1260->2048 on blocks 0,1 + knn2 partials for queries < 1024/batch
  fps_fin<<<dim3(34), dim3(512), 0, stream>>>(ppos, MWS, LPWS, fpws, out, PD2, PI2, 1260, 2048);
  // remaining knn2 partials (queries 1024..2047 per batch)
  knn2pb_k<<<dim3(32), dim3(512), 0, stream>>>(fpws, ppos, PD2, PI2);
  // pooling (inline merge of partials) -> output 0
  pool_k<<<dim3(4096), dim3(256), 0, stream>>>(x3, fpws, PD2, PI2, Wpool, out);
}

// Round 13
// 3220.455 us; speedup vs baseline: 1.1603x; 1.1603x over previous
//
#include <hip/hip_runtime.h>
#include <math.h>

// Sizes fixed by the problem
#define N_PTS   8192
#define BATCH   2
#define DIM     128
#define NOUT    2048
#define FPOFF   1048576   // 2048*2*256 floats of output 0
#define SLICE_MAX 1400    // >= max span per fps_slice call (fin = 1378!)

__device__ __forceinline__ float gelu_f(float v) {
  return 0.5f * v * (1.0f + erff(v * 0.70710678118654752440f));
}

// ---------------------------------------------------------------------------
// stable sorted top-8 insert, reference tie semantics (earlier insert wins)
// ---------------------------------------------------------------------------
__device__ __forceinline__ void knn_insert(float (&dist)[8], int (&idq)[8],
                                           float d2, int ci) {
  if (d2 < dist[7]) {
    float dd = d2;
#pragma unroll
    for (int j = 0; j < 8; ++j) {
      bool cc = dd < dist[j];
      float td = dist[j]; int ti = idq[j];
      dist[j] = cc ? dd : td; idq[j] = cc ? ci : ti;
      dd = cc ? td : dd; ci = cc ? ti : ci;
    }
  }
}

// ---------------------------------------------------------------------------
// FPS slice, 512 threads, 16 slots/thread — R10-EXACT inner loop (1.148us/it;
// the R11 LDS-coord-publish variant measured 1.61us/it and was reverted).
// u64 key (d_bits<<32)|~gidx; 6-stage wave butterfly; lane0 publishes key to
// parity LDS; ONE barrier; all threads scan 8 keys; winner coords fetched
// from global P by index (input-only, L2-hot same-address broadcast).
// State (mind, lp) persists in ws. Reference-exact: no-FMA fp32,
// (dx^2+dy^2)+dz^2, fminf, first-index tie-break via ~gidx under u64 max.
// ---------------------------------------------------------------------------
__device__ __forceinline__ void fps_slice(
    const float* __restrict__ P, float* __restrict__ MWS, float* __restrict__ LPWS,
    float* __restrict__ FPWS, float* __restrict__ OUTFP,
    int b, int t0, int t1)
{
  __builtin_amdgcn_s_setprio(3);
  __shared__ unsigned long long wkeys[2][8];
  __shared__ float hist[SLICE_MAX * 3];
  const int tid = threadIdx.x;          // 0..511
  const int wv = tid >> 6;              // 0..7
  const float* __restrict__ Pb = P + (long)b * N_PTS * 3;
  float px[16], py[16], pz[16], mind[16];
#pragma unroll
  for (int s = 0; s < 16; ++s) {
    int i = s * 512 + tid;
    px[s] = Pb[i * 3 + 0];
    py[s] = Pb[i * 3 + 1];
    pz[s] = Pb[i * 3 + 2];
  }
  float lx, ly, lz;
  if (t0 == 0) {
#pragma unroll
    for (int s = 0; s < 16; ++s) mind[s] = INFINITY;
    lx = Pb[0]; ly = Pb[1]; lz = Pb[2];
    if (tid == 0) { hist[0] = lx; hist[1] = ly; hist[2] = lz; }
  } else {
#pragma unroll
    for (int s = 0; s < 16; ++s) mind[s] = MWS[b * N_PTS + s * 512 + tid];
    lx = LPWS[b * 4 + 0]; ly = LPWS[b * 4 + 1]; lz = LPWS[b * 4 + 2];
  }
  const int tstart = (t0 == 0) ? 1 : t0;
  for (int t = tstart; t < t1; ++t) {
    const int par = t & 1;
    float bv = -INFINITY; int bs = 0;
#pragma unroll
    for (int s = 0; s < 16; ++s) {
      float dx = __fsub_rn(px[s], lx);
      float dy = __fsub_rn(py[s], ly);
      float dz = __fsub_rn(pz[s], lz);
      float d = __fadd_rn(__fadd_rn(__fmul_rn(dx, dx), __fmul_rn(dy, dy)), __fmul_rn(dz, dz));
      float mm = fminf(mind[s], d);
      mind[s] = mm;
      bool c = mm > bv;                 // strict > : earliest slot (smallest gidx) wins
      bv = c ? mm : bv; bs = c ? s : bs;
    }
    unsigned long long key =
        ((unsigned long long)__float_as_uint(bv) << 32) |
        (unsigned int)~(unsigned int)(bs * 512 + tid);
#pragma unroll
    for (int off = 1; off <= 32; off <<= 1) {
      unsigned long long o = __shfl_xor(key, off);
      key = (o > key) ? o : key;
    }
    if ((tid & 63) == 0) wkeys[par][wv] = key;   // all lanes converged; lane0 writes
    __syncthreads();
    unsigned long long wk = wkeys[par][0];
#pragma unroll
    for (int u = 1; u < 8; ++u) {
      unsigned long long o = wkeys[par][u];
      wk = (o > wk) ? o : wk;
    }
    const int idx = (int)(~(unsigned int)wk);    // lo32 = ~gidx
    lx = Pb[idx * 3 + 0];
    ly = Pb[idx * 3 + 1];
    lz = Pb[idx * 3 + 2];
    if (tid == 0) {
      int h = (t - t0) * 3;
      hist[h + 0] = lx; hist[h + 1] = ly; hist[h + 2] = lz;
    }
    // next iteration writes the other parity buffer -> one barrier suffices
  }
  // persist state
#pragma unroll
  for (int s = 0; s < 16; ++s) MWS[b * N_PTS + s * 512 + tid] = mind[s];
  if (tid == 0) { LPWS[b * 4 + 0] = lx; LPWS[b * 4 + 1] = ly; LPWS[b * 4 + 2] = lz; }
  __syncthreads();
  const int cnt = (t1 - t0) * 3;
  const long base = ((long)b * NOUT + t0) * 3;
  for (int i = tid; i < cnt; i += 512) {
    float v2 = hist[i];
    FPWS[base + i] = v2;
    OUTFP[FPOFF + base + i] = v2;
  }
  __builtin_amdgcn_s_setprio(0);
}

// ---------------------------------------------------------------------------
// Partial KNN2 body: query group qg (512 of the 4096 fp queries), candidate
// range r: [r*1024,(r+1)*1024). Batch-4 loop, LDS staging. Partial top-8 at
// [((b*NOUT+m)*8 + r)*8 + j].
// ---------------------------------------------------------------------------
__device__ __forceinline__ void knn2p_body(
    const float* __restrict__ Q, const float* __restrict__ Pp,
    float* __restrict__ PD, int* __restrict__ PI, int qg, int r)
{
  __shared__ float4 shp[512];
  const int b = qg >> 2;                 // 4 groups per batch
  const int m = (qg & 3) * 512 + threadIdx.x;
  const float qx = Q[(b * NOUT + m) * 3 + 0];
  const float qy = Q[(b * NOUT + m) * 3 + 1];
  const float qz = Q[(b * NOUT + m) * 3 + 2];
  const float sqq = __fadd_rn(__fadd_rn(__fmul_rn(qx, qx), __fmul_rn(qy, qy)), __fmul_rn(qz, qz));
  float dist[8]; int idq[8];
#pragma unroll
  for (int j = 0; j < 8; ++j) { dist[j] = INFINITY; idq[j] = 0; }
  const int cb = r * 1024;
  for (int tt = 0; tt < 1024; tt += 512) {
    __syncthreads();
    {
      int l = threadIdx.x;
      float x = Pp[(b * N_PTS + cb + tt + l) * 3 + 0];
      float y = Pp[(b * N_PTS + cb + tt + l) * 3 + 1];
      float z = Pp[(b * N_PTS + cb + tt + l) * 3 + 2];
      float s = __fadd_rn(__fadd_rn(__fmul_rn(x, x), __fmul_rn(y, y)), __fmul_rn(z, z));
      shp[l] = make_float4(x, y, z, s);
    }
    __syncthreads();
    for (int c = 0; c < 512; c += 4) {
      float4 p0 = shp[c + 0];
      float4 p1 = shp[c + 1];
      float4 p2 = shp[c + 2];
      float4 p3 = shp[c + 3];
      float d0 = __fsub_rn(__fadd_rn(sqq, p0.w), __fmul_rn(2.0f,
                 __fadd_rn(__fadd_rn(__fmul_rn(qx, p0.x), __fmul_rn(qy, p0.y)), __fmul_rn(qz, p0.z))));
      float d1 = __fsub_rn(__fadd_rn(sqq, p1.w), __fmul_rn(2.0f,
                 __fadd_rn(__fadd_rn(__fmul_rn(qx, p1.x), __fmul_rn(qy, p1.y)), __fmul_rn(qz, p1.z))));
      float d2 = __fsub_rn(__fadd_rn(sqq, p2.w), __fmul_rn(2.0f,
                 __fadd_rn(__fadd_rn(__fmul_rn(qx, p2.x), __fmul_rn(qy, p2.y)), __fmul_rn(qz, p2.z))));
      float d3 = __fsub_rn(__fadd_rn(sqq, p3.w), __fmul_rn(2.0f,
                 __fadd_rn(__fadd_rn(__fmul_rn(qx, p3.x), __fmul_rn(qy, p3.y)), __fmul_rn(qz, p3.z))));
      float mn = fminf(fminf(d0, d1), fminf(d2, d3));
      if (mn < dist[7]) {
        knn_insert(dist, idq, d0, cb + tt + c + 0);
        knn_insert(dist, idq, d1, cb + tt + c + 1);
        knn_insert(dist, idq, d2, cb + tt + c + 2);
        knn_insert(dist, idq, d3, cb + tt + c + 3);
      }
    }
  }
  const long ob = ((long)(b * NOUT + m) * 8 + r) * 8;
#pragma unroll
  for (int j = 0; j < 8; ++j) { PD[ob + j] = dist[j]; PI[ob + j] = idq[j]; }
}

// fps finisher; also hosts knn2p for query group gi=0 (queries < 512 per
// batch; complete since the hosted chain covered iters >= 670 before fin).
__global__ __launch_bounds__(512) void fps_fin(
    const float* __restrict__ P, float* __restrict__ MWS, float* __restrict__ LPWS,
    float* __restrict__ FPWS, float* __restrict__ OUTFP,
    float* __restrict__ PD2, int* __restrict__ PI2, int t0, int t1)
{
  if ((int)blockIdx.x < 2) {
    fps_slice(P, MWS, LPWS, FPWS, OUTFP, (int)blockIdx.x, t0, t1);
    return;
  }
  const int wid = (int)blockIdx.x - 2;   // 0..15
  const int qidx = wid >> 3;             // 0..1
  const int r = wid & 7;
  const int qg = qidx * 4;               // 0, 4 (gi = 0 for both batches)
  knn2p_body(FPWS, P, PD2, PI2, qg, r);
}

// remaining knn2 partials: gi in {1,2,3} per batch -> qg {1,2,3,5,6,7}
__global__ __launch_bounds__(512) void knn2pb_k(
    const float* __restrict__ Q, const float* __restrict__ Pp,
    float* __restrict__ PD, int* __restrict__ PI)
{
  const int qidx = (int)blockIdx.x >> 3;   // 0..5
  const int r = (int)blockIdx.x & 7;
  const int qg = (qidx < 3) ? (qidx + 1) : (qidx + 2);  // 1,2,3,5,6,7
  knn2p_body(Q, Pp, PD, PI, qg, r);
}

// ---------------------------------------------------------------------------
// Fused-pair fp32 GEMM host (512 threads = 2 teams x 256); blocks 0,1 = fps.
// ---------------------------------------------------------------------------
__global__ __launch_bounds__(512) void gemm2_k(
    const float* __restrict__ A, const float* __restrict__ W,
    const float* __restrict__ bias, float* __restrict__ OUT,
    const float* __restrict__ resid,
    int nbx, int N, int K, int a_mode, int o_mode, int act,
    const float* __restrict__ P, float* __restrict__ MWS, float* __restrict__ LPWS,
    float* __restrict__ FPWS, float* __restrict__ OUTFP, int t0, int t1)
{
  if ((int)blockIdx.x < 2) {
    fps_slice(P, MWS, LPWS, FPWS, OUTFP, (int)blockIdx.x, t0, t1);
    return;
  }
  const int wid = (int)blockIdx.x - 2;
  __shared__ float As[2][16][132];
  __shared__ float Ws2[2][16][132];
  const int team = threadIdx.x >> 8;
  const int tid = threadIdx.x & 255;
  const int tx = tid & 15, ty = tid >> 4;
  const int bx = wid % nbx;
  const int byy = (wid / nbx) * 2 + team;
  float acc[8][8];
#pragma unroll
  for (int i = 0; i < 8; ++i)
#pragma unroll
    for (int j = 0; j < 8; ++j) acc[i][j] = 0.f;

  for (int k0 = 0; k0 < K; k0 += 16) {
#pragma unroll
    for (int rep = 0; rep < 2; ++rep) {
      int qq = tid + rep * 256;          // 0..511
      int m = qq >> 2, kq = qq & 3;      // A: 128 rows x 16k as float4
      int r = byy * 128 + m;
      int arow = (a_mode == 1) ? ((r & 8191) * 2 + (r >> 13)) : r;
      const float4 av = *(const float4*)(A + (long)arow * K + k0 + kq * 4);
      As[team][kq * 4 + 0][m] = av.x; As[team][kq * 4 + 1][m] = av.y;
      As[team][kq * 4 + 2][m] = av.z; As[team][kq * 4 + 3][m] = av.w;
      int kw = qq >> 5, nq = qq & 31;    // W: 16k x 128 cols
      const float4 wv = *(const float4*)(W + (long)(k0 + kw) * N + bx * 128 + nq * 4);
      *(float4*)&Ws2[team][kw][nq * 4] = wv;
    }
    __syncthreads();
#pragma unroll
    for (int kk = 0; kk < 16; ++kk) {
      float4 a0 = *(const float4*)&As[team][kk][ty * 8];
      float4 a1 = *(const float4*)&As[team][kk][ty * 8 + 4];
      float4 w0 = *(const float4*)&Ws2[team][kk][tx * 4];
      float4 w1 = *(const float4*)&Ws2[team][kk][64 + tx * 4];
      float am[8] = {a0.x, a0.y, a0.z, a0.w, a1.x, a1.y, a1.z, a1.w};
      float wn[8] = {w0.x, w0.y, w0.z, w0.w, w1.x, w1.y, w1.z, w1.w};
#pragma unroll
      for (int i = 0; i < 8; ++i)
#pragma unroll
        for (int j = 0; j < 8; ++j) acc[i][j] += am[i] * wn[j];
    }
    __syncthreads();
  }
  const int c0 = bx * 128 + tx * 4;
  const int c1 = c0 + 64;
  float4 ba = *(const float4*)(bias + c0);
  float4 bb = *(const float4*)(bias + c1);
#pragma unroll
  for (int i = 0; i < 8; ++i) {
    int r = byy * 128 + ty * 8 + i;
    int orow = (o_mode == 1) ? ((r & 8191) * 2 + (r >> 13))
             : (o_mode == 2) ? ((r & 1) * 8192 + (r >> 1)) : r;
    float o[8] = {acc[i][0] + ba.x, acc[i][1] + ba.y, acc[i][2] + ba.z, acc[i][3] + ba.w,
                  acc[i][4] + bb.x, acc[i][5] + bb.y, acc[i][6] + bb.z, acc[i][7] + bb.w};
    if (act == 1) {
#pragma unroll
      for (int j = 0; j < 8; ++j) o[j] = gelu_f(o[j]);
    }
    if (resid) {
      float4 r0 = *(const float4*)(resid + (long)orow * N + c0);
      float4 r1 = *(const float4*)(resid + (long)orow * N + c1);
      o[0] += r0.x; o[1] += r0.y; o[2] += r0.z; o[3] += r0.w;
      o[4] += r1.x; o[5] += r1.y; o[6] += r1.z; o[7] += r1.w;
    }
    *(float4*)(OUT + (long)orow * N + c0) = make_float4(o[0], o[1], o[2], o[3]);
    *(float4*)(OUT + (long)orow * N + c1) = make_float4(o[4], o[5], o[6], o[7]);
  }
}

// ---------------------------------------------------------------------------
// Fused q,k,v GEMM host (one launch): 192 work blocks; sel = wid>>6 picks
// (Wq,qb) / (Wk,kb) / (Wv,vb); blocks 0,1 = fps. a_mode=1 row mapping.
// ---------------------------------------------------------------------------
__global__ __launch_bounds__(512) void gemmqkv_k(
    const float* __restrict__ A,
    const float* __restrict__ Wq, const float* __restrict__ bq, float* __restrict__ Oq,
    const float* __restrict__ Wk, const float* __restrict__ bk, float* __restrict__ Ok,
    const float* __restrict__ Wv, const float* __restrict__ bv, float* __restrict__ Ov,
    const float* __restrict__ P, float* __restrict__ MWS, float* __restrict__ LPWS,
    float* __restrict__ FPWS, float* __restrict__ OUTFP, int t0, int t1)
{
  if ((int)blockIdx.x < 2) {
    fps_slice(P, MWS, LPWS, FPWS, OUTFP, (int)blockIdx.x, t0, t1);
    return;
  }
  const int wid = (int)blockIdx.x - 2;   // 0..191
  const int sel = wid >> 6;              // 0=q 1=k 2=v
  const float* W = (sel == 0) ? Wq : (sel == 1) ? Wk : Wv;
  const float* bias = (sel == 0) ? bq : (sel == 1) ? bk : bv;
  float* OUT = (sel == 0) ? Oq : (sel == 1) ? Ok : Ov;
  __shared__ float As[2][16][132];
  __shared__ float Ws2[2][16][132];
  const int team = threadIdx.x >> 8;
  const int tid = threadIdx.x & 255;
  const int tx = tid & 15, ty = tid >> 4;
  const int byy = (wid & 63) * 2 + team;
  float acc[8][8];
#pragma unroll
  for (int i = 0; i < 8; ++i)
#pragma unroll
    for (int j = 0; j < 8; ++j) acc[i][j] = 0.f;

  for (int k0 = 0; k0 < 128; k0 += 16) {
#pragma unroll
    for (int rep = 0; rep < 2; ++rep) {
      int qq = tid + rep * 256;
      int m = qq >> 2, kq = qq & 3;
      int r = byy * 128 + m;
      int arow = (r & 8191) * 2 + (r >> 13);
      const float4 av = *(const float4*)(A + (long)arow * 128 + k0 + kq * 4);
      As[team][kq * 4 + 0][m] = av.x; As[team][kq * 4 + 1][m] = av.y;
      As[team][kq * 4 + 2][m] = av.z; As[team][kq * 4 + 3][m] = av.w;
      int kw = qq >> 5, nq = qq & 31;
      const float4 wv = *(const float4*)(W + (long)(k0 + kw) * 128 + nq * 4);
      *(float4*)&Ws2[team][kw][nq * 4] = wv;
    }
    __syncthreads();
#pragma unroll
    for (int kk = 0; kk < 16; ++kk) {
      float4 a0 = *(const float4*)&As[team][kk][ty * 8];
      float4 a1 = *(const float4*)&As[team][kk][ty * 8 + 4];
      float4 w0 = *(const float4*)&Ws2[team][kk][tx * 4];
      float4 w1 = *(const float4*)&Ws2[team][kk][64 + tx * 4];
      float am[8] = {a0.x, a0.y, a0.z, a0.w, a1.x, a1.y, a1.z, a1.w};
      float wn[8] = {w0.x, w0.y, w0.z, w0.w, w1.x, w1.y, w1.z, w1.w};
#pragma unroll
      for (int i = 0; i < 8; ++i)
#pragma unroll
        for (int j = 0; j < 8; ++j) acc[i][j] += am[i] * wn[j];
    }
    __syncthreads();
  }
  const int c0 = tx * 4;
  const int c1 = c0 + 64;
  float4 ba = *(const float4*)(bias + c0);
  float4 bb = *(const float4*)(bias + c1);
#pragma unroll
  for (int i = 0; i < 8; ++i) {
    int orow = byy * 128 + ty * 8 + i;
    float o[8] = {acc[i][0] + ba.x, acc[i][1] + ba.y, acc[i][2] + ba.z, acc[i][3] + ba.w,
                  acc[i][4] + bb.x, acc[i][5] + bb.y, acc[i][6] + bb.z, acc[i][7] + bb.w};
    *(float4*)(OUT + (long)orow * 128 + c0) = make_float4(o[0], o[1], o[2], o[3]);
    *(float4*)(OUT + (long)orow * 128 + c1) = make_float4(o[4], o[5], o[6], o[7]);
  }
}

// ---------------------------------------------------------------------------
// Partial KNN1 host (512 thr); blocks 0,1 = fps. 128 work blocks:
// wid = bid-2; qg = wid>>2 (32 groups of 512 queries); r = wid&3 (cand range).
// ---------------------------------------------------------------------------
__global__ __launch_bounds__(512) void knn1p_k(
    const float* __restrict__ Pp, float* __restrict__ PD, int* __restrict__ PI,
    const float* __restrict__ P, float* __restrict__ MWS, float* __restrict__ LPWS,
    float* __restrict__ FPWS, float* __restrict__ OUTFP, int t0, int t1)
{
  if ((int)blockIdx.x < 2) {
    fps_slice(P, MWS, LPWS, FPWS, OUTFP, (int)blockIdx.x, t0, t1);
    return;
  }
  const int wid = (int)blockIdx.x - 2;   // 0..127
  const int qg = wid >> 2;               // 0..31
  const int r = wid & 3;
  const int b = qg >> 4;                 // 16 groups per batch
  const int m = (qg & 15) * 512 + threadIdx.x;
  __shared__ float4 shp[512];
  const float qx = Pp[(b * N_PTS + m) * 3 + 0];
  const float qy = Pp[(b * N_PTS + m) * 3 + 1];
  const float qz = Pp[(b * N_PTS + m) * 3 + 2];
  const float sqq = __fadd_rn(__fadd_rn(__fmul_rn(qx, qx), __fmul_rn(qy, qy)), __fmul_rn(qz, qz));
  float dist[8]; int idq[8];
#pragma unroll
  for (int j = 0; j < 8; ++j) { dist[j] = INFINITY; idq[j] = 0; }
  const int cb = r * 2048;
  for (int tt = 0; tt < 2048; tt += 512) {
    __syncthreads();
    {
      int l = threadIdx.x;
      float x = Pp[(b * N_PTS + cb + tt + l) * 3 + 0];
      float y = Pp[(b * N_PTS + cb + tt + l) * 3 + 1];
      float z = Pp[(b * N_PTS + cb + tt + l) * 3 + 2];
      float s = __fadd_rn(__fadd_rn(__fmul_rn(x, x), __fmul_rn(y, y)), __fmul_rn(z, z));
      shp[l] = make_float4(x, y, z, s);
    }
    __syncthreads();
    for (int c = 0; c < 512; c += 4) {
      float4 p0 = shp[c + 0];
      float4 p1 = shp[c + 1];
      float4 p2 = shp[c + 2];
      float4 p3 = shp[c + 3];
      float d0 = __fsub_rn(__fadd_rn(sqq, p0.w), __fmul_rn(2.0f,
                 __fadd_rn(__fadd_rn(__fmul_rn(qx, p0.x), __fmul_rn(qy, p0.y)), __fmul_rn(qz, p0.z))));
      float d1 = __fsub_rn(__fadd_rn(sqq, p1.w), __fmul_rn(2.0f,
                 __fadd_rn(__fadd_rn(__fmul_rn(qx, p1.x), __fmul_rn(qy, p1.y)), __fmul_rn(qz, p1.z))));
      float d2 = __fsub_rn(__fadd_rn(sqq, p2.w), __fmul_rn(2.0f,
                 __fadd_rn(__fadd_rn(__fmul_rn(qx, p2.x), __fmul_rn(qy, p2.y)), __fmul_rn(qz, p2.z))));
      float d3 = __fsub_rn(__fadd_rn(sqq, p3.w), __fmul_rn(2.0f,
                 __fadd_rn(__fadd_rn(__fmul_rn(qx, p3.x), __fmul_rn(qy, p3.y)), __fmul_rn(qz, p3.z))));
      float mn = fminf(fminf(d0, d1), fminf(d2, d3));
      if (mn < dist[7]) {
        knn_insert(dist, idq, d0, cb + tt + c + 0);
        knn_insert(dist, idq, d1, cb + tt + c + 1);
        knn_insert(dist, idq, d2, cb + tt + c + 2);
        knn_insert(dist, idq, d3, cb + tt + c + 3);
      }
    }
  }
  const long ob = ((long)(b * N_PTS + m) * 4 + r) * 8;
#pragma unroll
  for (int j = 0; j < 8; ++j) { PD[ob + j] = dist[j]; PI[ob + j] = idq[j]; }
}

// ---------------------------------------------------------------------------
// Fused neighbor attention, 512-thr host; blocks 0,1 = fps.
// Merges the 4 knn1 partial lists inline per wave (ranges in ascending index
// order -> identical tie semantics to a monolithic scan).
// ---------------------------------------------------------------------------
__global__ __launch_bounds__(512) void attn_k(
    const float* __restrict__ Qb, const float* __restrict__ Kb, const float* __restrict__ Vb,
    const float* __restrict__ Pp,
    const float* __restrict__ PD1, const int* __restrict__ PI1,
    const float* __restrict__ Wpe1, const float* __restrict__ bpe1,
    const float* __restrict__ Wpe2, const float* __restrict__ bpe2,
    const float* __restrict__ Wg, const float* __restrict__ bg,
    float* __restrict__ RES,
    const float* __restrict__ P, float* __restrict__ MWS, float* __restrict__ LPWS,
    float* __restrict__ FPWS, float* __restrict__ OUTFP, int t0, int t1)
{
  if ((int)blockIdx.x < 2) {
    fps_slice(P, MWS, LPWS, FPWS, OUTFP, (int)blockIdx.x, t0, t1);
    return;
  }
  __shared__ float sbuf[8][1024];
  const int tid = threadIdx.x;
  const int w = tid >> 6, lane = tid & 63;
  const int g = ((int)blockIdx.x - 2) * 8 + w;   // 0..16383 : b*8192+n
  const int b = g >> 13, n = g & 8191;
  const int j0 = lane * 2;
  float* sb = sbuf[w];
  const float2 qv = *(const float2*)(Qb + (long)g * 128 + j0);
  // inline merge of 4 partial top-8 lists (wave-uniform, broadcast loads)
  float mdist[8]; int nb[8];
#pragma unroll
  for (int j = 0; j < 8; ++j) { mdist[j] = INFINITY; nb[j] = 0; }
#pragma unroll
  for (int r = 0; r < 4; ++r) {
    const long ob = ((long)g * 4 + r) * 8;
#pragma unroll
    for (int j = 0; j < 8; ++j) knn_insert(mdist, nb, PD1[ob + j], PI1[ob + j]);
  }
  const float p0 = Pp[(b * N_PTS + n) * 3 + 0];
  const float p1 = Pp[(b * N_PTS + n) * 3 + 1];
  const float p2 = Pp[(b * N_PTS + n) * 3 + 2];
  // phase A: h1 = gelu(rel @ Wpe1 + bpe1) -> LDS
  const float2 w1a = *(const float2*)(Wpe1 + j0);
  const float2 w1b = *(const float2*)(Wpe1 + 128 + j0);
  const float2 w1c = *(const float2*)(Wpe1 + 256 + j0);
  const float2 b1 = *(const float2*)(bpe1 + j0);
#pragma unroll
  for (int kk = 0; kk < 8; ++kk) {
    const float* pn = Pp + (long)(b * N_PTS + nb[kk]) * 3;
    float r0 = p0 - pn[0], r1 = p1 - pn[1], r2 = p2 - pn[2];
    float h0 = r0 * w1a.x + r1 * w1b.x + r2 * w1c.x + b1.x;
    float h1 = r0 * w1a.y + r1 * w1b.y + r2 * w1c.y + b1.y;
    sb[kk * 128 + j0]     = gelu_f(h0);
    sb[kk * 128 + j0 + 1] = gelu_f(h1);
  }
  __syncthreads();
  // phase B: pe = h1 @ Wpe2
  float2 pe[8];
#pragma unroll
  for (int kk = 0; kk < 8; ++kk) pe[kk] = make_float2(0.f, 0.f);
  for (int i = 0; i < 128; i += 2) {
    float2 wa = *(const float2*)(Wpe2 + (long)i * 128 + j0);
    float2 wb = *(const float2*)(Wpe2 + (long)(i + 1) * 128 + j0);
#pragma unroll
    for (int kk = 0; kk < 8; ++kk) {
      float2 hh = *(const float2*)&sb[kk * 128 + i];
      pe[kk].x += hh.x * wa.x + hh.y * wb.x;
      pe[kk].y += hh.x * wa.y + hh.y * wb.y;
    }
  }
  const float2 b2v = *(const float2*)(bpe2 + j0);
  __syncthreads();
  // t = q - k_nb + pe  -> LDS (reuse buffer)
#pragma unroll
  for (int kk = 0; kk < 8; ++kk) {
    pe[kk].x += b2v.x; pe[kk].y += b2v.y;
    const float2 kv = *(const float2*)(Kb + (long)(b * N_PTS + nb[kk]) * 128 + j0);
    sb[kk * 128 + j0]     = qv.x - kv.x + pe[kk].x;
    sb[kk * 128 + j0 + 1] = qv.y - kv.y + pe[kk].y;
  }
  __syncthreads();
  // phase C: a = t @ Wg
  float2 av[8];
#pragma unroll
  for (int kk = 0; kk < 8; ++kk) av[kk] = make_float2(0.f, 0.f);
  for (int i = 0; i < 128; i += 2) {
    float2 wa = *(const float2*)(Wg + (long)i * 128 + j0);
    float2 wb = *(const float2*)(Wg + (long)(i + 1) * 128 + j0);
#pragma unroll
    for (int kk = 0; kk < 8; ++kk) {
      float2 tt = *(const float2*)&sb[kk * 128 + i];
      av[kk].x += tt.x * wa.x + tt.y * wb.x;
      av[kk].y += tt.x * wa.y + tt.y * wb.y;
    }
  }
  const float2 bgv = *(const float2*)(bg + j0);
  float2 resv = make_float2(0.f, 0.f);
  const float sd = 11.313708498984761f;   // sqrt(128)
#pragma unroll
  for (int kk = 0; kk < 8; ++kk) {
    float l0 = (av[kk].x + bgv.x) / sd;
    float l1 = (av[kk].y + bgv.y) / sd;
    float mx = fmaxf(l0, l1);
#pragma unroll
    for (int off = 32; off >= 1; off >>= 1) mx = fmaxf(mx, __shfl_xor(mx, off));
    float e0 = expf(l0 - mx), e1 = expf(l1 - mx);
    float sm = e0 + e1;
#pragma unroll
    for (int off = 32; off >= 1; off >>= 1) sm += __shfl_xor(sm, off);
    const float2 vv = *(const float2*)(Vb + (long)(b * N_PTS + nb[kk]) * 128 + j0);
    resv.x += (e0 / sm) * (vv.x + pe[kk].x);
    resv.y += (e1 / sm) * (vv.y + pe[kk].y);
  }
  *(float2*)(RES + (long)g * 128 + j0) = resv;
}

// ---------------------------------------------------------------------------
// RMSNorm in-place, 512-thr host (8 rows/block); blocks 0,1 = fps.
// ---------------------------------------------------------------------------
__global__ __launch_bounds__(512) void rms_k(
    float* __restrict__ X, const float* __restrict__ scale,
    const float* __restrict__ P, float* __restrict__ MWS, float* __restrict__ LPWS,
    float* __restrict__ FPWS, float* __restrict__ OUTFP, int t0, int t1)
{
  if ((int)blockIdx.x < 2) {
    fps_slice(P, MWS, LPWS, FPWS, OUTFP, (int)blockIdx.x, t0, t1);
    return;
  }
  const int tid = threadIdx.x;
  const int w = tid >> 6, lane = tid & 63;
  const long row = (long)((int)blockIdx.x - 2) * 8 + w;
  float2 xv = *(float2*)(X + row * 128 + lane * 2);
  float ss = xv.x * xv.x + xv.y * xv.y;
#pragma unroll
  for (int off = 32; off >= 1; off >>= 1) ss += __shfl_xor(ss, off);
  const float rms = sqrtf(ss) / 11.313708498984761f;
  const float den = rms + 1e-8f;
  const float2 sc = *(const float2*)(scale + lane * 2);
  float2 o;
  o.x = sc.x * (xv.x / den);
  o.y = sc.y * (xv.y / den);
  *(float2*)(X + row * 128 + lane * 2) = o;
}

// ---------------------------------------------------------------------------
// PointPool with inline merge of the 8 knn2 partial lists per output point.
// ---------------------------------------------------------------------------
__global__ __launch_bounds__(256) void pool_k(
    const float* __restrict__ X3, const float* __restrict__ FPWS,
    const float* __restrict__ PD2, const int* __restrict__ PI2,
    const float* __restrict__ Wp, float* __restrict__ OUT)
{
  __shared__ float sh[8][256];
  __shared__ float fp3[3];
  const int bm = blockIdx.x;           // b*2048 + m
  const int b = bm >> 11;
  const int m = bm & 2047;
  const int tid = threadIdx.x;
  // inline merge (block-uniform, broadcast loads)
  float mdist[8]; int kidx[8];
#pragma unroll
  for (int j = 0; j < 8; ++j) { mdist[j] = INFINITY; kidx[j] = 0; }
#pragma unroll
  for (int r = 0; r < 8; ++r) {
    const long ob = ((long)bm * 8 + r) * 8;
#pragma unroll
    for (int j = 0; j < 8; ++j) knn_insert(mdist, kidx, PD2[ob + j], PI2[ob + j]);
  }
#pragma unroll
  for (int kk = 0; kk < 8; ++kk) {
    sh[kk][tid] = X3[(long)(b * N_PTS + kidx[kk]) * 256 + tid];
  }
  if (tid < 3) fp3[tid] = FPWS[bm * 3 + tid];
  __syncthreads();
  float base = fp3[0] * Wp[tid] + fp3[1] * Wp[256 + tid] + fp3[2] * Wp[512 + tid];
  float acc[8];
#pragma unroll
  for (int kk = 0; kk < 8; ++kk) acc[kk] = base;
  for (int i = 0; i < 256; i += 2) {
    float w0 = Wp[(3 + i) * 256 + tid];
    float w1 = Wp[(4 + i) * 256 + tid];
#pragma unroll
    for (int kk = 0; kk < 8; ++kk) {
      float2 hh = *(const float2*)&sh[kk][i];
      acc[kk] += hh.x * w0 + hh.y * w1;
    }
  }
  float mx = -INFINITY;
#pragma unroll
  for (int kk = 0; kk < 8; ++kk) {
    float a = acc[kk];
    a = (a >= 0.f) ? a : 0.01f * a;      // LeakyReLU(0.01)
    mx = fmaxf(mx, a);
  }
  OUT[(long)(m * 2 + b) * 256 + tid] = mx;   // (n_out, B, 2D)
}

// ---------------------------------------------------------------------------
extern "C" void kernel_launch(void* const* d_in, const int* in_sizes, int n_in,
                              void* d_out, int out_size, void* d_ws, size_t ws_size,
                              hipStream_t stream)
{
  (void)in_sizes; (void)n_in; (void)out_size; (void)ws_size;
  const float* x    = (const float*)d_in[0];
  const float* ppos = (const float*)d_in[1];
  const float* Wq = (const float*)d_in[2];   const float* bq = (const float*)d_in[3];
  const float* Wk = (const float*)d_in[4];   const float* bk = (const float*)d_in[5];
  const float* Wv = (const float*)d_in[6];   const float* bv = (const float*)d_in[7];
  const float* Wpe1 = (const float*)d_in[8]; const float* bpe1 = (const float*)d_in[9];
  const float* Wpe2 = (const float*)d_in[10];const float* bpe2 = (const float*)d_in[11];
  const float* Wg = (const float*)d_in[12];  const float* bg = (const float*)d_in[13];
  const float* Wo = (const float*)d_in[14];  const float* bo = (const float*)d_in[15];
  const float* scale = (const float*)d_in[16];
  const float* Wf1 = (const float*)d_in[17]; const float* bf1 = (const float*)d_in[18];
  const float* Wf2 = (const float*)d_in[19]; const float* bf2 = (const float*)d_in[20];
  const float* Wpool = (const float*)d_in[21];
  float* out = (float*)d_out;
  char* ws = (char*)d_ws;

  // workspace layout (peak ~49 MB, aliased):
  float* qb   = (float*)(ws);                                   // 8 MB (B,N,128)
  float* kb   = (float*)(ws + (size_t)8 * 1024 * 1024);         // 8 MB
  float* vb   = (float*)(ws + (size_t)16 * 1024 * 1024);        // 8 MB
  float* res  = (float*)(ws + (size_t)24 * 1024 * 1024);        // 8 MB
  float* x2   = (float*)(ws + (size_t)32 * 1024 * 1024);        // 8 MB (N,B,128)
  float* hbuf = (float*)(ws);                                   // 32 MB, aliases qb..res
  float* x3   = (float*)(ws + (size_t)32 * 1024 * 1024);        // 16 MB (B,N,256), aliases x2
  // knn1 partials in the x2 slot (consumed by attn BEFORE Wo writes x2)
  float* PD1  = (float*)(ws + (size_t)32 * 1024 * 1024);        // 2 MB
  int*   PI1  = (int*)  (ws + (size_t)34 * 1024 * 1024);        // 2 MB
  // knn2 partials in the hbuf slot (dead after ffn2; written in fin and later)
  float* PD2  = (float*)(ws);                                   // 1 MB
  int*   PI2  = (int*)  (ws + (size_t)1 * 1024 * 1024);         // 1 MB
  char*  tail = ws + (size_t)48 * 1024 * 1024;
  float* fpws = (float*)(tail);                       // 64 KB slot (48 used)
  float* MWS  = (float*)(tail + 65536);               // 64 KB fps mind state
  float* LPWS = (float*)(tail + 131072);              // 4 KB fps lp state

  // fps spans (sum = 2048): qkv 40, knn1p 60, attn 420, Wo 30, rms 20,
  // ffn1 60, ffn2 40 -> hosted 670; fin 1378 (SLICE_MAX=1400 covers it).
  gemmqkv_k<<<dim3(194), dim3(512), 0, stream>>>(x, Wq, bq, qb, Wk, bk, kb, Wv, bv, vb,
                                                 ppos, MWS, LPWS, fpws, out, 0, 40);
  knn1p_k<<<dim3(130), dim3(512), 0, stream>>>(ppos, PD1, PI1,
                                               ppos, MWS, LPWS, fpws, out, 40, 100);
  attn_k<<<dim3(2050), dim3(512), 0, stream>>>(qb, kb, vb, ppos, PD1, PI1,
                                               Wpe1, bpe1, Wpe2, bpe2, Wg, bg, res,
                                               ppos, MWS, LPWS, fpws, out, 100, 520);
  gemm2_k<<<dim3(66), dim3(512), 0, stream>>>(res, Wo, bo, x2, x, 1, 128, 128, 0, 1, 0,
                                              ppos, MWS, LPWS, fpws, out, 520, 550);
  rms_k<<<dim3(2050), dim3(512), 0, stream>>>(x2, scale,
                                              ppos, MWS, LPWS, fpws, out, 550, 570);
  gemm2_k<<<dim3(258), dim3(512), 0, stream>>>(x2, Wf1, bf1, hbuf, nullptr, 4, 512, 128, 0, 0, 1,
                                               ppos, MWS, LPWS, fpws, out, 570, 630);
  gemm2_k<<<dim3(130), dim3(512), 0, stream>>>(hbuf, Wf2, bf2, x3, nullptr, 2, 256, 512, 0, 2, 0,
                                               ppos, MWS, LPWS, fpws, out, 630, 670);
  // fin: fps 670->2048 on blocks 0,1 + knn2 partials for queries < 512/batch
  fps_fin<<<dim3(18), dim3(512), 0, stream>>>(ppos, MWS, LPWS, fpws, out, PD2, PI2, 670, 2048);
  // remaining knn2 partials (queries 512..2047 per batch)
  knn2pb_k<<<dim3(48), dim3(512), 0, stream>>>(fpws, ppos, PD2, PI2);
  // pooling (inline merge of partials) -> output 0
  pool_k<<<dim3(4096), dim3(256), 0, stream>>>(x3, fpws, PD2, PI2, Wpool, out);
}

// Round 14
// 2986.043 us; speedup vs baseline: 1.2514x; 1.0785x over previous
//
#include <hip/hip_runtime.h>
#include <math.h>

// Sizes fixed by the problem
#define N_PTS   8192
#define BATCH   2
#define DIM     128
#define NOUT    2048
#define FPOFF   1048576   // 2048*2*256 floats of output 0
#define SLICE_MAX 1000    // >= max span per fps_slice call (fin = 918)

__device__ __forceinline__ float gelu_f(float v) {
  return 0.5f * v * (1.0f + erff(v * 0.70710678118654752440f));
}

// ---------------------------------------------------------------------------
// stable sorted top-8 insert, reference tie semantics (earlier insert wins)
// ---------------------------------------------------------------------------
__device__ __forceinline__ void knn_insert(float (&dist)[8], int (&idq)[8],
                                           float d2, int ci) {
  if (d2 < dist[7]) {
    float dd = d2;
#pragma unroll
    for (int j = 0; j < 8; ++j) {
      bool cc = dd < dist[j];
      float td = dist[j]; int ti = idq[j];
      dist[j] = cc ? dd : td; idq[j] = cc ? ci : ti;
      dd = cc ? td : dd; ci = cc ? ti : ci;
    }
  }
}

// ---------------------------------------------------------------------------
// FPS slice, 512 threads, 16 slots/thread — R10/R13-proven loop (1.143us/it).
// u64 key (d_bits<<32)|~gidx; 6-stage wave butterfly; lane0 publishes key to
// parity LDS; ONE barrier; all threads scan 8 keys; winner coords fetched
// from global P by index (input-only, L2-hot same-address broadcast).
// State (mind, lp) persists in ws. Reference-exact: no-FMA fp32,
// (dx^2+dy^2)+dz^2, fminf, first-index tie-break via ~gidx under u64 max.
// ---------------------------------------------------------------------------
__device__ __forceinline__ void fps_slice(
    const float* __restrict__ P, float* __restrict__ MWS, float* __restrict__ LPWS,
    float* __restrict__ FPWS, float* __restrict__ OUTFP,
    int b, int t0, int t1)
{
  __builtin_amdgcn_s_setprio(3);
  __shared__ unsigned long long wkeys[2][8];
  __shared__ float hist[SLICE_MAX * 3];
  const int tid = threadIdx.x;          // 0..511
  const int wv = tid >> 6;              // 0..7
  const float* __restrict__ Pb = P + (long)b * N_PTS * 3;
  float px[16], py[16], pz[16], mind[16];
#pragma unroll
  for (int s = 0; s < 16; ++s) {
    int i = s * 512 + tid;
    px[s] = Pb[i * 3 + 0];
    py[s] = Pb[i * 3 + 1];
    pz[s] = Pb[i * 3 + 2];
  }
  float lx, ly, lz;
  if (t0 == 0) {
#pragma unroll
    for (int s = 0; s < 16; ++s) mind[s] = INFINITY;
    lx = Pb[0]; ly = Pb[1]; lz = Pb[2];
    if (tid == 0) { hist[0] = lx; hist[1] = ly; hist[2] = lz; }
  } else {
#pragma unroll
    for (int s = 0; s < 16; ++s) mind[s] = MWS[b * N_PTS + s * 512 + tid];
    lx = LPWS[b * 4 + 0]; ly = LPWS[b * 4 + 1]; lz = LPWS[b * 4 + 2];
  }
  const int tstart = (t0 == 0) ? 1 : t0;
  for (int t = tstart; t < t1; ++t) {
    const int par = t & 1;
    float bv = -INFINITY; int bs = 0;
#pragma unroll
    for (int s = 0; s < 16; ++s) {
      float dx = __fsub_rn(px[s], lx);
      float dy = __fsub_rn(py[s], ly);
      float dz = __fsub_rn(pz[s], lz);
      float d = __fadd_rn(__fadd_rn(__fmul_rn(dx, dx), __fmul_rn(dy, dy)), __fmul_rn(dz, dz));
      float mm = fminf(mind[s], d);
      mind[s] = mm;
      bool c = mm > bv;                 // strict > : earliest slot (smallest gidx) wins
      bv = c ? mm : bv; bs = c ? s : bs;
    }
    unsigned long long key =
        ((unsigned long long)__float_as_uint(bv) << 32) |
        (unsigned int)~(unsigned int)(bs * 512 + tid);
#pragma unroll
    for (int off = 1; off <= 32; off <<= 1) {
      unsigned long long o = __shfl_xor(key, off);
      key = (o > key) ? o : key;
    }
    if ((tid & 63) == 0) wkeys[par][wv] = key;   // all lanes converged; lane0 writes
    __syncthreads();
    unsigned long long wk = wkeys[par][0];
#pragma unroll
    for (int u = 1; u < 8; ++u) {
      unsigned long long o = wkeys[par][u];
      wk = (o > wk) ? o : wk;
    }
    const int idx = (int)(~(unsigned int)wk);    // lo32 = ~gidx
    lx = Pb[idx * 3 + 0];
    ly = Pb[idx * 3 + 1];
    lz = Pb[idx * 3 + 2];
    if (tid == 0) {
      int h = (t - t0) * 3;
      hist[h + 0] = lx; hist[h + 1] = ly; hist[h + 2] = lz;
    }
    // next iteration writes the other parity buffer -> one barrier suffices
  }
  // persist state
#pragma unroll
  for (int s = 0; s < 16; ++s) MWS[b * N_PTS + s * 512 + tid] = mind[s];
  if (tid == 0) { LPWS[b * 4 + 0] = lx; LPWS[b * 4 + 1] = ly; LPWS[b * 4 + 2] = lz; }
  __syncthreads();
  const int cnt = (t1 - t0) * 3;
  const long base = ((long)b * NOUT + t0) * 3;
  for (int i = tid; i < cnt; i += 512) {
    float v2 = hist[i];
    FPWS[base + i] = v2;
    OUTFP[FPOFF + base + i] = v2;
  }
  __builtin_amdgcn_s_setprio(0);
}

// ---------------------------------------------------------------------------
// Partial KNN2 body: query group qg (512 of the 4096 fp queries), candidate
// range r: [r*1024,(r+1)*1024). Batch-4 loop, LDS staging. Partial top-8 at
// [((b*NOUT+m)*8 + r)*8 + j].
// ---------------------------------------------------------------------------
__device__ __forceinline__ void knn2p_body(
    const float* __restrict__ Q, const float* __restrict__ Pp,
    float* __restrict__ PD, int* __restrict__ PI, int qg, int r)
{
  __shared__ float4 shp[512];
  const int b = qg >> 2;                 // 4 groups per batch
  const int m = (qg & 3) * 512 + threadIdx.x;
  const float qx = Q[(b * NOUT + m) * 3 + 0];
  const float qy = Q[(b * NOUT + m) * 3 + 1];
  const float qz = Q[(b * NOUT + m) * 3 + 2];
  const float sqq = __fadd_rn(__fadd_rn(__fmul_rn(qx, qx), __fmul_rn(qy, qy)), __fmul_rn(qz, qz));
  float dist[8]; int idq[8];
#pragma unroll
  for (int j = 0; j < 8; ++j) { dist[j] = INFINITY; idq[j] = 0; }
  const int cb = r * 1024;
  for (int tt = 0; tt < 1024; tt += 512) {
    __syncthreads();
    {
      int l = threadIdx.x;
      float x = Pp[(b * N_PTS + cb + tt + l) * 3 + 0];
      float y = Pp[(b * N_PTS + cb + tt + l) * 3 + 1];
      float z = Pp[(b * N_PTS + cb + tt + l) * 3 + 2];
      float s = __fadd_rn(__fadd_rn(__fmul_rn(x, x), __fmul_rn(y, y)), __fmul_rn(z, z));
      shp[l] = make_float4(x, y, z, s);
    }
    __syncthreads();
    for (int c = 0; c < 512; c += 4) {
      float4 p0 = shp[c + 0];
      float4 p1 = shp[c + 1];
      float4 p2 = shp[c + 2];
      float4 p3 = shp[c + 3];
      float d0 = __fsub_rn(__fadd_rn(sqq, p0.w), __fmul_rn(2.0f,
                 __fadd_rn(__fadd_rn(__fmul_rn(qx, p0.x), __fmul_rn(qy, p0.y)), __fmul_rn(qz, p0.z))));
      float d1 = __fsub_rn(__fadd_rn(sqq, p1.w), __fmul_rn(2.0f,
                 __fadd_rn(__fadd_rn(__fmul_rn(qx, p1.x), __fmul_rn(qy, p1.y)), __fmul_rn(qz, p1.z))));
      float d2 = __fsub_rn(__fadd_rn(sqq, p2.w), __fmul_rn(2.0f,
                 __fadd_rn(__fadd_rn(__fmul_rn(qx, p2.x), __fmul_rn(qy, p2.y)), __fmul_rn(qz, p2.z))));
      float d3 = __fsub_rn(__fadd_rn(sqq, p3.w), __fmul_rn(2.0f,
                 __fadd_rn(__fadd_rn(__fmul_rn(qx, p3.x), __fmul_rn(qy, p3.y)), __fmul_rn(qz, p3.z))));
      float mn = fminf(fminf(d0, d1), fminf(d2, d3));
      if (mn < dist[7]) {
        knn_insert(dist, idq, d0, cb + tt + c + 0);
        knn_insert(dist, idq, d1, cb + tt + c + 1);
        knn_insert(dist, idq, d2, cb + tt + c + 2);
        knn_insert(dist, idq, d3, cb + tt + c + 3);
      }
    }
  }
  const long ob = ((long)(b * NOUT + m) * 8 + r) * 8;
#pragma unroll
  for (int j = 0; j < 8; ++j) { PD[ob + j] = dist[j]; PI[ob + j] = idq[j]; }
}

// fps finisher; also hosts knn2p for query group gi=0 (queries < 512 per
// batch; complete since the hosted chain covered iters >= 1130 before fin).
__global__ __launch_bounds__(512) void fps_fin(
    const float* __restrict__ P, float* __restrict__ MWS, float* __restrict__ LPWS,
    float* __restrict__ FPWS, float* __restrict__ OUTFP,
    float* __restrict__ PD2, int* __restrict__ PI2, int t0, int t1)
{
  if ((int)blockIdx.x < 2) {
    fps_slice(P, MWS, LPWS, FPWS, OUTFP, (int)blockIdx.x, t0, t1);
    return;
  }
  const int wid = (int)blockIdx.x - 2;   // 0..15
  const int qidx = wid >> 3;             // 0..1
  const int r = wid & 7;
  const int qg = qidx * 4;               // 0, 4 (gi = 0 for both batches)
  knn2p_body(FPWS, P, PD2, PI2, qg, r);
}

// remaining knn2 partials: gi in {1,2,3} per batch -> qg {1,2,3,5,6,7}
__global__ __launch_bounds__(512) void knn2pb_k(
    const float* __restrict__ Q, const float* __restrict__ Pp,
    float* __restrict__ PD, int* __restrict__ PI)
{
  const int qidx = (int)blockIdx.x >> 3;   // 0..5
  const int r = (int)blockIdx.x & 7;
  const int qg = (qidx < 3) ? (qidx + 1) : (qidx + 2);  // 1,2,3,5,6,7
  knn2p_body(Q, Pp, PD, PI, qg, r);
}

// ---------------------------------------------------------------------------
// Fused-pair fp32 GEMM host (512 threads = 2 teams x 256); blocks 0,1 = fps.
// act: 0 none, 1 gelu, 2 row-RMSNorm (requires N==128, resid) using scale.
// ---------------------------------------------------------------------------
__global__ __launch_bounds__(512) void gemm2_k(
    const float* __restrict__ A, const float* __restrict__ W,
    const float* __restrict__ bias, float* __restrict__ OUT,
    const float* __restrict__ resid, const float* __restrict__ scale,
    int nbx, int N, int K, int a_mode, int o_mode, int act,
    const float* __restrict__ P, float* __restrict__ MWS, float* __restrict__ LPWS,
    float* __restrict__ FPWS, float* __restrict__ OUTFP, int t0, int t1)
{
  if ((int)blockIdx.x < 2) {
    fps_slice(P, MWS, LPWS, FPWS, OUTFP, (int)blockIdx.x, t0, t1);
    return;
  }
  const int wid = (int)blockIdx.x - 2;
  __shared__ float As[2][16][132];
  __shared__ float Ws2[2][16][132];
  const int team = threadIdx.x >> 8;
  const int tid = threadIdx.x & 255;
  const int tx = tid & 15, ty = tid >> 4;
  const int bx = wid % nbx;
  const int byy = (wid / nbx) * 2 + team;
  float acc[8][8];
#pragma unroll
  for (int i = 0; i < 8; ++i)
#pragma unroll
    for (int j = 0; j < 8; ++j) acc[i][j] = 0.f;

  for (int k0 = 0; k0 < K; k0 += 16) {
#pragma unroll
    for (int rep = 0; rep < 2; ++rep) {
      int qq = tid + rep * 256;          // 0..511
      int m = qq >> 2, kq = qq & 3;      // A: 128 rows x 16k as float4
      int r = byy * 128 + m;
      int arow = (a_mode == 1) ? ((r & 8191) * 2 + (r >> 13)) : r;
      const float4 av = *(const float4*)(A + (long)arow * K + k0 + kq * 4);
      As[team][kq * 4 + 0][m] = av.x; As[team][kq * 4 + 1][m] = av.y;
      As[team][kq * 4 + 2][m] = av.z; As[team][kq * 4 + 3][m] = av.w;
      int kw = qq >> 5, nq = qq & 31;    // W: 16k x 128 cols
      const float4 wv = *(const float4*)(W + (long)(k0 + kw) * N + bx * 128 + nq * 4);
      *(float4*)&Ws2[team][kw][nq * 4] = wv;
    }
    __syncthreads();
#pragma unroll
    for (int kk = 0; kk < 16; ++kk) {
      float4 a0 = *(const float4*)&As[team][kk][ty * 8];
      float4 a1 = *(const float4*)&As[team][kk][ty * 8 + 4];
      float4 w0 = *(const float4*)&Ws2[team][kk][tx * 4];
      float4 w1 = *(const float4*)&Ws2[team][kk][64 + tx * 4];
      float am[8] = {a0.x, a0.y, a0.z, a0.w, a1.x, a1.y, a1.z, a1.w};
      float wn[8] = {w0.x, w0.y, w0.z, w0.w, w1.x, w1.y, w1.z, w1.w};
#pragma unroll
      for (int i = 0; i < 8; ++i)
#pragma unroll
        for (int j = 0; j < 8; ++j) acc[i][j] += am[i] * wn[j];
    }
    __syncthreads();
  }
  const int c0 = bx * 128 + tx * 4;
  const int c1 = c0 + 64;
  float4 ba = *(const float4*)(bias + c0);
  float4 bb = *(const float4*)(bias + c1);
  float4 sa = make_float4(1.f, 1.f, 1.f, 1.f), sb2 = sa;
  if (act == 2) {
    sa  = *(const float4*)(scale + c0);
    sb2 = *(const float4*)(scale + c1);
  }
#pragma unroll
  for (int i = 0; i < 8; ++i) {
    int r = byy * 128 + ty * 8 + i;
    int orow = (o_mode == 1) ? ((r & 8191) * 2 + (r >> 13))
             : (o_mode == 2) ? ((r & 1) * 8192 + (r >> 1)) : r;
    float o[8] = {acc[i][0] + ba.x, acc[i][1] + ba.y, acc[i][2] + ba.z, acc[i][3] + ba.w,
                  acc[i][4] + bb.x, acc[i][5] + bb.y, acc[i][6] + bb.z, acc[i][7] + bb.w};
    if (act == 1) {
#pragma unroll
      for (int j = 0; j < 8; ++j) o[j] = gelu_f(o[j]);
    }
    if (resid) {
      float4 r0 = *(const float4*)(resid + (long)orow * N + c0);
      float4 r1 = *(const float4*)(resid + (long)orow * N + c1);
      o[0] += r0.x; o[1] += r0.y; o[2] += r0.z; o[3] += r0.w;
      o[4] += r1.x; o[5] += r1.y; o[6] += r1.z; o[7] += r1.w;
    }
    if (act == 2) {
      // row RMS over the 128 cols held by the 16 same-ty threads (one wave
      // sub-group: lanes differ only in the low 4 bits)
      float ss = 0.f;
#pragma unroll
      for (int j = 0; j < 8; ++j) ss += o[j] * o[j];
#pragma unroll
      for (int off = 1; off <= 8; off <<= 1) ss += __shfl_xor(ss, off);
      const float den = sqrtf(ss) / 11.313708498984761f + 1e-8f;
      float sc[8] = {sa.x, sa.y, sa.z, sa.w, sb2.x, sb2.y, sb2.z, sb2.w};
#pragma unroll
      for (int j = 0; j < 8; ++j) o[j] = sc[j] * (o[j] / den);
    }
    *(float4*)(OUT + (long)orow * N + c0) = make_float4(o[0], o[1], o[2], o[3]);
    *(float4*)(OUT + (long)orow * N + c1) = make_float4(o[4], o[5], o[6], o[7]);
  }
}

// ---------------------------------------------------------------------------
// Fused q,k,v GEMM host (one launch): 192 work blocks; sel = wid>>6 picks
// (Wq,qb) / (Wk,kb) / (Wv,vb); blocks 0,1 = fps. a_mode=1 row mapping.
// ---------------------------------------------------------------------------
__global__ __launch_bounds__(512) void gemmqkv_k(
    const float* __restrict__ A,
    const float* __restrict__ Wq, const float* __restrict__ bq, float* __restrict__ Oq,
    const float* __restrict__ Wk, const float* __restrict__ bk, float* __restrict__ Ok,
    const float* __restrict__ Wv, const float* __restrict__ bv, float* __restrict__ Ov,
    const float* __restrict__ P, float* __restrict__ MWS, float* __restrict__ LPWS,
    float* __restrict__ FPWS, float* __restrict__ OUTFP, int t0, int t1)
{
  if ((int)blockIdx.x < 2) {
    fps_slice(P, MWS, LPWS, FPWS, OUTFP, (int)blockIdx.x, t0, t1);
    return;
  }
  const int wid = (int)blockIdx.x - 2;   // 0..191
  const int sel = wid >> 6;              // 0=q 1=k 2=v
  const float* W = (sel == 0) ? Wq : (sel == 1) ? Wk : Wv;
  const float* bias = (sel == 0) ? bq : (sel == 1) ? bk : bv;
  float* OUT = (sel == 0) ? Oq : (sel == 1) ? Ok : Ov;
  __shared__ float As[2][16][132];
  __shared__ float Ws2[2][16][132];
  const int team = threadIdx.x >> 8;
  const int tid = threadIdx.x & 255;
  const int tx = tid & 15, ty = tid >> 4;
  const int byy = (wid & 63) * 2 + team;
  float acc[8][8];
#pragma unroll
  for (int i = 0; i < 8; ++i)
#pragma unroll
    for (int j = 0; j < 8; ++j) acc[i][j] = 0.f;

  for (int k0 = 0; k0 < 128; k0 += 16) {
#pragma unroll
    for (int rep = 0; rep < 2; ++rep) {
      int qq = tid + rep * 256;
      int m = qq >> 2, kq = qq & 3;
      int r = byy * 128 + m;
      int arow = (r & 8191) * 2 + (r >> 13);
      const float4 av = *(const float4*)(A + (long)arow * 128 + k0 + kq * 4);
      As[team][kq * 4 + 0][m] = av.x; As[team][kq * 4 + 1][m] = av.y;
      As[team][kq * 4 + 2][m] = av.z; As[team][kq * 4 + 3][m] = av.w;
      int kw = qq >> 5, nq = qq & 31;
      const float4 wv = *(const float4*)(W + (long)(k0 + kw) * 128 + nq * 4);
      *(float4*)&Ws2[team][kw][nq * 4] = wv;
    }
    __syncthreads();
#pragma unroll
    for (int kk = 0; kk < 16; ++kk) {
      float4 a0 = *(const float4*)&As[team][kk][ty * 8];
      float4 a1 = *(const float4*)&As[team][kk][ty * 8 + 4];
      float4 w0 = *(const float4*)&Ws2[team][kk][tx * 4];
      float4 w1 = *(const float4*)&Ws2[team][kk][64 + tx * 4];
      float am[8] = {a0.x, a0.y, a0.z, a0.w, a1.x, a1.y, a1.z, a1.w};
      float wn[8] = {w0.x, w0.y, w0.z, w0.w, w1.x, w1.y, w1.z, w1.w};
#pragma unroll
      for (int i = 0; i < 8; ++i)
#pragma unroll
        for (int j = 0; j < 8; ++j) acc[i][j] += am[i] * wn[j];
    }
    __syncthreads();
  }
  const int c0 = tx * 4;
  const int c1 = c0 + 64;
  float4 ba = *(const float4*)(bias + c0);
  float4 bb = *(const float4*)(bias + c1);
#pragma unroll
  for (int i = 0; i < 8; ++i) {
    int orow = byy * 128 + ty * 8 + i;
    float o[8] = {acc[i][0] + ba.x, acc[i][1] + ba.y, acc[i][2] + ba.z, acc[i][3] + ba.w,
                  acc[i][4] + bb.x, acc[i][5] + bb.y, acc[i][6] + bb.z, acc[i][7] + bb.w};
    *(float4*)(OUT + (long)orow * 128 + c0) = make_float4(o[0], o[1], o[2], o[3]);
    *(float4*)(OUT + (long)orow * 128 + c1) = make_float4(o[4], o[5], o[6], o[7]);
  }
}

// ---------------------------------------------------------------------------
// Partial KNN1 host (512 thr); blocks 0,1 = fps. 128 work blocks:
// wid = bid-2; qg = wid>>2 (32 groups of 512 queries); r = wid&3 (cand range).
// ---------------------------------------------------------------------------
__global__ __launch_bounds__(512) void knn1p_k(
    const float* __restrict__ Pp, float* __restrict__ PD, int* __restrict__ PI,
    const float* __restrict__ P, float* __restrict__ MWS, float* __restrict__ LPWS,
    float* __restrict__ FPWS, float* __restrict__ OUTFP, int t0, int t1)
{
  if ((int)blockIdx.x < 2) {
    fps_slice(P, MWS, LPWS, FPWS, OUTFP, (int)blockIdx.x, t0, t1);
    return;
  }
  const int wid = (int)blockIdx.x - 2;   // 0..127
  const int qg = wid >> 2;               // 0..31
  const int r = wid & 3;
  const int b = qg >> 4;                 // 16 groups per batch
  const int m = (qg & 15) * 512 + threadIdx.x;
  __shared__ float4 shp[512];
  const float qx = Pp[(b * N_PTS + m) * 3 + 0];
  const float qy = Pp[(b * N_PTS + m) * 3 + 1];
  const float qz = Pp[(b * N_PTS + m) * 3 + 2];
  const float sqq = __fadd_rn(__fadd_rn(__fmul_rn(qx, qx), __fmul_rn(qy, qy)), __fmul_rn(qz, qz));
  float dist[8]; int idq[8];
#pragma unroll
  for (int j = 0; j < 8; ++j) { dist[j] = INFINITY; idq[j] = 0; }
  const int cb = r * 2048;
  for (int tt = 0; tt < 2048; tt += 512) {
    __syncthreads();
    {
      int l = threadIdx.x;
      float x = Pp[(b * N_PTS + cb + tt + l) * 3 + 0];
      float y = Pp[(b * N_PTS + cb + tt + l) * 3 + 1];
      float z = Pp[(b * N_PTS + cb + tt + l) * 3 + 2];
      float s = __fadd_rn(__fadd_rn(__fmul_rn(x, x), __fmul_rn(y, y)), __fmul_rn(z, z));
      shp[l] = make_float4(x, y, z, s);
    }
    __syncthreads();
    for (int c = 0; c < 512; c += 4) {
      float4 p0 = shp[c + 0];
      float4 p1 = shp[c + 1];
      float4 p2 = shp[c + 2];
      float4 p3 = shp[c + 3];
      float d0 = __fsub_rn(__fadd_rn(sqq, p0.w), __fmul_rn(2.0f,
                 __fadd_rn(__fadd_rn(__fmul_rn(qx, p0.x), __fmul_rn(qy, p0.y)), __fmul_rn(qz, p0.z))));
      float d1 = __fsub_rn(__fadd_rn(sqq, p1.w), __fmul_rn(2.0f,
                 __fadd_rn(__fadd_rn(__fmul_rn(qx, p1.x), __fmul_rn(qy, p1.y)), __fmul_rn(qz, p1.z))));
      float d2 = __fsub_rn(__fadd_rn(sqq, p2.w), __fmul_rn(2.0f,
                 __fadd_rn(__fadd_rn(__fmul_rn(qx, p2.x), __fmul_rn(qy, p2.y)), __fmul_rn(qz, p2.z))));
      float d3 = __fsub_rn(__fadd_rn(sqq, p3.w), __fmul_rn(2.0f,
                 __fadd_rn(__fadd_rn(__fmul_rn(qx, p3.x), __fmul_rn(qy, p3.y)), __fmul_rn(qz, p3.z))));
      float mn = fminf(fminf(d0, d1), fminf(d2, d3));
      if (mn < dist[7]) {
        knn_insert(dist, idq, d0, cb + tt + c + 0);
        knn_insert(dist, idq, d1, cb + tt + c + 1);
        knn_insert(dist, idq, d2, cb + tt + c + 2);
        knn_insert(dist, idq, d3, cb + tt + c + 3);
      }
    }
  }
  const long ob = ((long)(b * N_PTS + m) * 4 + r) * 8;
#pragma unroll
  for (int j = 0; j < 8; ++j) { PD[ob + j] = dist[j]; PI[ob + j] = idq[j]; }
}

// ---------------------------------------------------------------------------
// Fused neighbor attention, 512-thr host; blocks 0,1 = fps.
// Merges the 4 knn1 partial lists inline per wave (ranges in ascending index
// order -> identical tie semantics to a monolithic scan).
// ---------------------------------------------------------------------------
__global__ __launch_bounds__(512) void attn_k(
    const float* __restrict__ Qb, const float* __restrict__ Kb, const float* __restrict__ Vb,
    const float* __restrict__ Pp,
    const float* __restrict__ PD1, const int* __restrict__ PI1,
    const float* __restrict__ Wpe1, const float* __restrict__ bpe1,
    const float* __restrict__ Wpe2, const float* __restrict__ bpe2,
    const float* __restrict__ Wg, const float* __restrict__ bg,
    float* __restrict__ RES,
    const float* __restrict__ P, float* __restrict__ MWS, float* __restrict__ LPWS,
    float* __restrict__ FPWS, float* __restrict__ OUTFP, int t0, int t1)
{
  if ((int)blockIdx.x < 2) {
    fps_slice(P, MWS, LPWS, FPWS, OUTFP, (int)blockIdx.x, t0, t1);
    return;
  }
  __shared__ float sbuf[8][1024];
  const int tid = threadIdx.x;
  const int w = tid >> 6, lane = tid & 63;
  const int g = ((int)blockIdx.x - 2) * 8 + w;   // 0..16383 : b*8192+n
  const int b = g >> 13, n = g & 8191;
  const int j0 = lane * 2;
  float* sb = sbuf[w];
  const float2 qv = *(const float2*)(Qb + (long)g * 128 + j0);
  // inline merge of 4 partial top-8 lists (wave-uniform, broadcast loads)
  float mdist[8]; int nb[8];
#pragma unroll
  for (int j = 0; j < 8; ++j) { mdist[j] = INFINITY; nb[j] = 0; }
#pragma unroll
  for (int r = 0; r < 4; ++r) {
    const long ob = ((long)g * 4 + r) * 8;
#pragma unroll
    for (int j = 0; j < 8; ++j) knn_insert(mdist, nb, PD1[ob + j], PI1[ob + j]);
  }
  const float p0 = Pp[(b * N_PTS + n) * 3 + 0];
  const float p1 = Pp[(b * N_PTS + n) * 3 + 1];
  const float p2 = Pp[(b * N_PTS + n) * 3 + 2];
  // phase A: h1 = gelu(rel @ Wpe1 + bpe1) -> LDS
  const float2 w1a = *(const float2*)(Wpe1 + j0);
  const float2 w1b = *(const float2*)(Wpe1 + 128 + j0);
  const float2 w1c = *(const float2*)(Wpe1 + 256 + j0);
  const float2 b1 = *(const float2*)(bpe1 + j0);
#pragma unroll
  for (int kk = 0; kk < 8; ++kk) {
    const float* pn = Pp + (long)(b * N_PTS + nb[kk]) * 3;
    float r0 = p0 - pn[0], r1 = p1 - pn[1], r2 = p2 - pn[2];
    float h0 = r0 * w1a.x + r1 * w1b.x + r2 * w1c.x + b1.x;
    float h1 = r0 * w1a.y + r1 * w1b.y + r2 * w1c.y + b1.y;
    sb[kk * 128 + j0]     = gelu_f(h0);
    sb[kk * 128 + j0 + 1] = gelu_f(h1);
  }
  __syncthreads();
  // phase B: pe = h1 @ Wpe2
  float2 pe[8];
#pragma unroll
  for (int kk = 0; kk < 8; ++kk) pe[kk] = make_float2(0.f, 0.f);
  for (int i = 0; i < 128; i += 2) {
    float2 wa = *(const float2*)(Wpe2 + (long)i * 128 + j0);
    float2 wb = *(const float2*)(Wpe2 + (long)(i + 1) * 128 + j0);
#pragma unroll
    for (int kk = 0; kk < 8; ++kk) {
      float2 hh = *(const float2*)&sb[kk * 128 + i];
      pe[kk].x += hh.x * wa.x + hh.y * wb.x;
      pe[kk].y += hh.x * wa.y + hh.y * wb.y;
    }
  }
  const float2 b2v = *(const float2*)(bpe2 + j0);
  __syncthreads();
  // t = q - k_nb + pe  -> LDS (reuse buffer)
#pragma unroll
  for (int kk = 0; kk < 8; ++kk) {
    pe[kk].x += b2v.x; pe[kk].y += b2v.y;
    const float2 kv = *(const float2*)(Kb + (long)(b * N_PTS + nb[kk]) * 128 + j0);
    sb[kk * 128 + j0]     = qv.x - kv.x + pe[kk].x;
    sb[kk * 128 + j0 + 1] = qv.y - kv.y + pe[kk].y;
  }
  __syncthreads();
  // phase C: a = t @ Wg
  float2 av[8];
#pragma unroll
  for (int kk = 0; kk < 8; ++kk) av[kk] = make_float2(0.f, 0.f);
  for (int i = 0; i < 128; i += 2) {
    float2 wa = *(const float2*)(Wg + (long)i * 128 + j0);
    float2 wb = *(const float2*)(Wg + (long)(i + 1) * 128 + j0);
#pragma unroll
    for (int kk = 0; kk < 8; ++kk) {
      float2 tt = *(const float2*)&sb[kk * 128 + i];
      av[kk].x += tt.x * wa.x + tt.y * wb.x;
      av[kk].y += tt.x * wa.y + tt.y * wb.y;
    }
  }
  const float2 bgv = *(const float2*)(bg + j0);
  float2 resv = make_float2(0.f, 0.f);
  const float sd = 11.313708498984761f;   // sqrt(128)
#pragma unroll
  for (int kk = 0; kk < 8; ++kk) {
    float l0 = (av[kk].x + bgv.x) / sd;
    float l1 = (av[kk].y + bgv.y) / sd;
    float mx = fmaxf(l0, l1);
#pragma unroll
    for (int off = 32; off >= 1; off >>= 1) mx = fmaxf(mx, __shfl_xor(mx, off));
    float e0 = expf(l0 - mx), e1 = expf(l1 - mx);
    float sm = e0 + e1;
#pragma unroll
    for (int off = 32; off >= 1; off >>= 1) sm += __shfl_xor(sm, off);
    const float2 vv = *(const float2*)(Vb + (long)(b * N_PTS + nb[kk]) * 128 + j0);
    resv.x += (e0 / sm) * (vv.x + pe[kk].x);
    resv.y += (e1 / sm) * (vv.y + pe[kk].y);
  }
  *(float2*)(RES + (long)g * 128 + j0) = resv;
}

// ---------------------------------------------------------------------------
// PointPool with inline merge of the 8 knn2 partial lists per output point.
// ---------------------------------------------------------------------------
__global__ __launch_bounds__(256) void pool_k(
    const float* __restrict__ X3, const float* __restrict__ FPWS,
    const float* __restrict__ PD2, const int* __restrict__ PI2,
    const float* __restrict__ Wp, float* __restrict__ OUT)
{
  __shared__ float sh[8][256];
  __shared__ float fp3[3];
  const int bm = blockIdx.x;           // b*2048 + m
  const int b = bm >> 11;
  const int m = bm & 2047;
  const int tid = threadIdx.x;
  // inline merge (block-uniform, broadcast loads)
  float mdist[8]; int kidx[8];
#pragma unroll
  for (int j = 0; j < 8; ++j) { mdist[j] = INFINITY; kidx[j] = 0; }
#pragma unroll
  for (int r = 0; r < 8; ++r) {
    const long ob = ((long)bm * 8 + r) * 8;
#pragma unroll
    for (int j = 0; j < 8; ++j) knn_insert(mdist, kidx, PD2[ob + j], PI2[ob + j]);
  }
#pragma unroll
  for (int kk = 0; kk < 8; ++kk) {
    sh[kk][tid] = X3[(long)(b * N_PTS + kidx[kk]) * 256 + tid];
  }
  if (tid < 3) fp3[tid] = FPWS[bm * 3 + tid];
  __syncthreads();
  float base = fp3[0] * Wp[tid] + fp3[1] * Wp[256 + tid] + fp3[2] * Wp[512 + tid];
  float acc[8];
#pragma unroll
  for (int kk = 0; kk < 8; ++kk) acc[kk] = base;
  for (int i = 0; i < 256; i += 2) {
    float w0 = Wp[(3 + i) * 256 + tid];
    float w1 = Wp[(4 + i) * 256 + tid];
#pragma unroll
    for (int kk = 0; kk < 8; ++kk) {
      float2 hh = *(const float2*)&sh[kk][i];
      acc[kk] += hh.x * w0 + hh.y * w1;
    }
  }
  float mx = -INFINITY;
#pragma unroll
  for (int kk = 0; kk < 8; ++kk) {
    float a = acc[kk];
    a = (a >= 0.f) ? a : 0.01f * a;      // LeakyReLU(0.01)
    mx = fmaxf(mx, a);
  }
  OUT[(long)(m * 2 + b) * 256 + tid] = mx;   // (n_out, B, 2D)
}

// ---------------------------------------------------------------------------
extern "C" void kernel_launch(void* const* d_in, const int* in_sizes, int n_in,
                              void* d_out, int out_size, void* d_ws, size_t ws_size,
                              hipStream_t stream)
{
  (void)in_sizes; (void)n_in; (void)out_size; (void)ws_size;
  const float* x    = (const float*)d_in[0];
  const float* ppos = (const float*)d_in[1];
  const float* Wq = (const float*)d_in[2];   const float* bq = (const float*)d_in[3];
  const float* Wk = (const float*)d_in[4];   const float* bk = (const float*)d_in[5];
  const float* Wv = (const float*)d_in[6];   const float* bv = (const float*)d_in[7];
  const float* Wpe1 = (const float*)d_in[8]; const float* bpe1 = (const float*)d_in[9];
  const float* Wpe2 = (const float*)d_in[10];const float* bpe2 = (const float*)d_in[11];
  const float* Wg = (const float*)d_in[12];  const float* bg = (const float*)d_in[13];
  const float* Wo = (const float*)d_in[14];  const float* bo = (const float*)d_in[15];
  const float* scale = (const float*)d_in[16];
  const float* Wf1 = (const float*)d_in[17]; const float* bf1 = (const float*)d_in[18];
  const float* Wf2 = (const float*)d_in[19]; const float* bf2 = (const float*)d_in[20];
  const float* Wpool = (const float*)d_in[21];
  float* out = (float*)d_out;
  char* ws = (char*)d_ws;

  // workspace layout (peak ~49 MB, aliased):
  float* qb   = (float*)(ws);                                   // 8 MB (B,N,128)
  float* kb   = (float*)(ws + (size_t)8 * 1024 * 1024);         // 8 MB
  float* vb   = (float*)(ws + (size_t)16 * 1024 * 1024);        // 8 MB
  float* res  = (float*)(ws + (size_t)24 * 1024 * 1024);        // 8 MB
  float* x2   = (float*)(ws + (size_t)32 * 1024 * 1024);        // 8 MB (N,B,128)
  float* hbuf = (float*)(ws);                                   // 32 MB, aliases qb..res
  float* x3   = (float*)(ws + (size_t)32 * 1024 * 1024);        // 16 MB (B,N,256), aliases x2
  // knn1 partials in the x2 slot (consumed by attn BEFORE Wo writes x2)
  float* PD1  = (float*)(ws + (size_t)32 * 1024 * 1024);        // 2 MB
  int*   PI1  = (int*)  (ws + (size_t)34 * 1024 * 1024);        // 2 MB
  // knn2 partials in the hbuf slot (dead after ffn2; written in fin and later)
  float* PD2  = (float*)(ws);                                   // 1 MB
  int*   PI2  = (int*)  (ws + (size_t)1 * 1024 * 1024);         // 1 MB
  char*  tail = ws + (size_t)48 * 1024 * 1024;
  float* fpws = (float*)(tail);                       // 64 KB slot (48 used)
  float* MWS  = (float*)(tail + 65536);               // 64 KB fps mind state
  float* LPWS = (float*)(tail + 131072);              // 4 KB fps lp state

  // fps spans (sum = 2048): qkv 170, knn1p 200, attn 420, Wo+rms 70,
  // ffn1 180, ffn2 90 -> hosted 1130; fin 918 (SLICE_MAX=1000 covers it).
  gemmqkv_k<<<dim3(194), dim3(512), 0, stream>>>(x, Wq, bq, qb, Wk, bk, kb, Wv, bv, vb,
                                                 ppos, MWS, LPWS, fpws, out, 0, 170);
  knn1p_k<<<dim3(130), dim3(512), 0, stream>>>(ppos, PD1, PI1,
                                               ppos, MWS, LPWS, fpws, out, 170, 370);
  attn_k<<<dim3(2050), dim3(512), 0, stream>>>(qb, kb, vb, ppos, PD1, PI1,
                                               Wpe1, bpe1, Wpe2, bpe2, Wg, bg, res,
                                               ppos, MWS, LPWS, fpws, out, 370, 790);
  // Wo + residual + fused RMSNorm -> x2
  gemm2_k<<<dim3(66), dim3(512), 0, stream>>>(res, Wo, bo, x2, x, scale, 1, 128, 128, 0, 1, 2,
                                              ppos, MWS, LPWS, fpws, out, 790, 860);
  gemm2_k<<<dim3(258), dim3(512), 0, stream>>>(x2, Wf1, bf1, hbuf, nullptr, nullptr, 4, 512, 128, 0, 0, 1,
                                               ppos, MWS, LPWS, fpws, out, 860, 1040);
  gemm2_k<<<dim3(130), dim3(512), 0, stream>>>(hbuf, Wf2, bf2, x3, nullptr, nullptr, 2, 256, 512, 0, 2, 0,
                                               ppos, MWS, LPWS, fpws, out, 1040, 1130);
  // fin: fps 1130->2048 on blocks 0,1 + knn2 partials for queries < 512/batch
  fps_fin<<<dim3(18), dim3(512), 0, stream>>>(ppos, MWS, LPWS, fpws, out, PD2, PI2, 1130, 2048);
  // remaining knn2 partials (queries 512..2047 per batch)
  knn2pb_k<<<dim3(48), dim3(512), 0, stream>>>(fpws, ppos, PD2, PI2);
  // pooling (inline merge of partials) -> output 0
  pool_k<<<dim3(4096), dim3(256), 0, stream>>>(x3, fpws, PD2, PI2, Wpool, out);
}

// Round 15
// 2947.423 us; speedup vs baseline: 1.2677x; 1.0131x over previous
//
#include <hip/hip_runtime.h>
#include <math.h>

// Sizes fixed by the problem
#define N_PTS   8192
#define BATCH   2
#define DIM     128
#define NOUT    2048
#define FPOFF   1048576   // 2048*2*256 floats of output 0
#define SLICE_MAX 560     // >= max span per fps_slice call (attn = 540)

__device__ __forceinline__ float gelu_f(float v) {
  return 0.5f * v * (1.0f + erff(v * 0.70710678118654752440f));
}

// ---------------------------------------------------------------------------
// stable sorted top-8 insert, reference tie semantics (earlier insert wins)
// ---------------------------------------------------------------------------
__device__ __forceinline__ void knn_insert(float (&dist)[8], int (&idq)[8],
                                           float d2, int ci) {
  if (d2 < dist[7]) {
    float dd = d2;
#pragma unroll
    for (int j = 0; j < 8; ++j) {
      bool cc = dd < dist[j];
      float td = dist[j]; int ti = idq[j];
      dist[j] = cc ? dd : td; idq[j] = cc ? ci : ti;
      dd = cc ? td : dd; ci = cc ? ti : ci;
    }
  }
}

// ---------------------------------------------------------------------------
// FPS slice, 512 threads, 16 slots/thread — R10/R13/R14-proven (1.144us/it).
// u64 key (d_bits<<32)|~gidx; 6-stage wave butterfly; lane0 publishes key to
// parity LDS; ONE barrier; all threads scan 8 keys; winner coords fetched
// from global P by index (input-only, L2-hot same-address broadcast).
// State (mind, lp) persists in ws. Reference-exact: no-FMA fp32,
// (dx^2+dy^2)+dz^2, fminf, first-index tie-break via ~gidx under u64 max.
// ---------------------------------------------------------------------------
__device__ __forceinline__ void fps_slice(
    const float* __restrict__ P, float* __restrict__ MWS, float* __restrict__ LPWS,
    float* __restrict__ FPWS, float* __restrict__ OUTFP,
    int b, int t0, int t1)
{
  __builtin_amdgcn_s_setprio(3);
  __shared__ unsigned long long wkeys[2][8];
  __shared__ float hist[SLICE_MAX * 3];
  const int tid = threadIdx.x;          // 0..511
  const int wv = tid >> 6;              // 0..7
  const float* __restrict__ Pb = P + (long)b * N_PTS * 3;
  float px[16], py[16], pz[16], mind[16];
#pragma unroll
  for (int s = 0; s < 16; ++s) {
    int i = s * 512 + tid;
    px[s] = Pb[i * 3 + 0];
    py[s] = Pb[i * 3 + 1];
    pz[s] = Pb[i * 3 + 2];
  }
  float lx, ly, lz;
  if (t0 == 0) {
#pragma unroll
    for (int s = 0; s < 16; ++s) mind[s] = INFINITY;
    lx = Pb[0]; ly = Pb[1]; lz = Pb[2];
    if (tid == 0) { hist[0] = lx; hist[1] = ly; hist[2] = lz; }
  } else {
#pragma unroll
    for (int s = 0; s < 16; ++s) mind[s] = MWS[b * N_PTS + s * 512 + tid];
    lx = LPWS[b * 4 + 0]; ly = LPWS[b * 4 + 1]; lz = LPWS[b * 4 + 2];
  }
  const int tstart = (t0 == 0) ? 1 : t0;
  for (int t = tstart; t < t1; ++t) {
    const int par = t & 1;
    float bv = -INFINITY; int bs = 0;
#pragma unroll
    for (int s = 0; s < 16; ++s) {
      float dx = __fsub_rn(px[s], lx);
      float dy = __fsub_rn(py[s], ly);
      float dz = __fsub_rn(pz[s], lz);
      float d = __fadd_rn(__fadd_rn(__fmul_rn(dx, dx), __fmul_rn(dy, dy)), __fmul_rn(dz, dz));
      float mm = fminf(mind[s], d);
      mind[s] = mm;
      bool c = mm > bv;                 // strict > : earliest slot (smallest gidx) wins
      bv = c ? mm : bv; bs = c ? s : bs;
    }
    unsigned long long key =
        ((unsigned long long)__float_as_uint(bv) << 32) |
        (unsigned int)~(unsigned int)(bs * 512 + tid);
#pragma unroll
    for (int off = 1; off <= 32; off <<= 1) {
      unsigned long long o = __shfl_xor(key, off);
      key = (o > key) ? o : key;
    }
    if ((tid & 63) == 0) wkeys[par][wv] = key;   // all lanes converged; lane0 writes
    __syncthreads();
    unsigned long long wk = wkeys[par][0];
#pragma unroll
    for (int u = 1; u < 8; ++u) {
      unsigned long long o = wkeys[par][u];
      wk = (o > wk) ? o : wk;
    }
    const int idx = (int)(~(unsigned int)wk);    // lo32 = ~gidx
    lx = Pb[idx * 3 + 0];
    ly = Pb[idx * 3 + 1];
    lz = Pb[idx * 3 + 2];
    if (tid == 0) {
      int h = (t - t0) * 3;
      hist[h + 0] = lx; hist[h + 1] = ly; hist[h + 2] = lz;
    }
    // next iteration writes the other parity buffer -> one barrier suffices
  }
  // persist state
#pragma unroll
  for (int s = 0; s < 16; ++s) MWS[b * N_PTS + s * 512 + tid] = mind[s];
  if (tid == 0) { LPWS[b * 4 + 0] = lx; LPWS[b * 4 + 1] = ly; LPWS[b * 4 + 2] = lz; }
  __syncthreads();
  const int cnt = (t1 - t0) * 3;
  const long base = ((long)b * NOUT + t0) * 3;
  for (int i = tid; i < cnt; i += 512) {
    float v2 = hist[i];
    FPWS[base + i] = v2;
    OUTFP[FPOFF + base + i] = v2;
  }
  __builtin_amdgcn_s_setprio(0);
}

// ---------------------------------------------------------------------------
// Partial KNN2 body: query group qg (512 of the 4096 fp queries), candidate
// range r: [r*1024,(r+1)*1024). Batch-4 loop, LDS staging. Partial top-8 at
// [((b*NOUT+m)*8 + r)*8 + j].
// ---------------------------------------------------------------------------
__device__ __forceinline__ void knn2p_body(
    const float* __restrict__ Q, const float* __restrict__ Pp,
    float* __restrict__ PD, int* __restrict__ PI, int qg, int r)
{
  __shared__ float4 shp[512];
  const int b = qg >> 2;                 // 4 groups per batch
  const int m = (qg & 3) * 512 + threadIdx.x;
  const float qx = Q[(b * NOUT + m) * 3 + 0];
  const float qy = Q[(b * NOUT + m) * 3 + 1];
  const float qz = Q[(b * NOUT + m) * 3 + 2];
  const float sqq = __fadd_rn(__fadd_rn(__fmul_rn(qx, qx), __fmul_rn(qy, qy)), __fmul_rn(qz, qz));
  float dist[8]; int idq[8];
#pragma unroll
  for (int j = 0; j < 8; ++j) { dist[j] = INFINITY; idq[j] = 0; }
  const int cb = r * 1024;
  for (int tt = 0; tt < 1024; tt += 512) {
    __syncthreads();
    {
      int l = threadIdx.x;
      float x = Pp[(b * N_PTS + cb + tt + l) * 3 + 0];
      float y = Pp[(b * N_PTS + cb + tt + l) * 3 + 1];
      float z = Pp[(b * N_PTS + cb + tt + l) * 3 + 2];
      float s = __fadd_rn(__fadd_rn(__fmul_rn(x, x), __fmul_rn(y, y)), __fmul_rn(z, z));
      shp[l] = make_float4(x, y, z, s);
    }
    __syncthreads();
    for (int c = 0; c < 512; c += 4) {
      float4 p0 = shp[c + 0];
      float4 p1 = shp[c + 1];
      float4 p2 = shp[c + 2];
      float4 p3 = shp[c + 3];
      float d0 = __fsub_rn(__fadd_rn(sqq, p0.w), __fmul_rn(2.0f,
                 __fadd_rn(__fadd_rn(__fmul_rn(qx, p0.x), __fmul_rn(qy, p0.y)), __fmul_rn(qz, p0.z))));
      float d1 = __fsub_rn(__fadd_rn(sqq, p1.w), __fmul_rn(2.0f,
                 __fadd_rn(__fadd_rn(__fmul_rn(qx, p1.x), __fmul_rn(qy, p1.y)), __fmul_rn(qz, p1.z))));
      float d2 = __fsub_rn(__fadd_rn(sqq, p2.w), __fmul_rn(2.0f,
                 __fadd_rn(__fadd_rn(__fmul_rn(qx, p2.x), __fmul_rn(qy, p2.y)), __fmul_rn(qz, p2.z))));
      float d3 = __fsub_rn(__fadd_rn(sqq, p3.w), __fmul_rn(2.0f,
                 __fadd_rn(__fadd_rn(__fmul_rn(qx, p3.x), __fmul_rn(qy, p3.y)), __fmul_rn(qz, p3.z))));
      float mn = fminf(fminf(d0, d1), fminf(d2, d3));
      if (mn < dist[7]) {
        knn_insert(dist, idq, d0, cb + tt + c + 0);
        knn_insert(dist, idq, d1, cb + tt + c + 1);
        knn_insert(dist, idq, d2, cb + tt + c + 2);
        knn_insert(dist, idq, d3, cb + tt + c + 3);
      }
    }
  }
  const long ob = ((long)(b * NOUT + m) * 8 + r) * 8;
#pragma unroll
  for (int j = 0; j < 8; ++j) { PD[ob + j] = dist[j]; PI[ob + j] = idq[j]; }
}

// fps finisher; also hosts knn2p for query group gi=0 (queries < 512 per
// batch; complete since the hosted chain covered iters >= 1530 before fin).
__global__ __launch_bounds__(512) void fps_fin(
    const float* __restrict__ P, float* __restrict__ MWS, float* __restrict__ LPWS,
    float* __restrict__ FPWS, float* __restrict__ OUTFP,
    float* __restrict__ PD2, int* __restrict__ PI2, int t0, int t1)
{
  if ((int)blockIdx.x < 2) {
    fps_slice(P, MWS, LPWS, FPWS, OUTFP, (int)blockIdx.x, t0, t1);
    return;
  }
  const int wid = (int)blockIdx.x - 2;   // 0..15
  const int qidx = wid >> 3;             // 0..1
  const int r = wid & 7;
  const int qg = qidx * 4;               // 0, 4 (gi = 0 for both batches)
  knn2p_body(FPWS, P, PD2, PI2, qg, r);
}

// remaining knn2 partials: gi in {1,2,3} per batch -> qg {1,2,3,5,6,7}
__global__ __launch_bounds__(512) void knn2pb_k(
    const float* __restrict__ Q, const float* __restrict__ Pp,
    float* __restrict__ PD, int* __restrict__ PI)
{
  const int qidx = (int)blockIdx.x >> 3;   // 0..5
  const int r = (int)blockIdx.x & 7;
  const int qg = (qidx < 3) ? (qidx + 1) : (qidx + 2);  // 1,2,3,5,6,7
  knn2p_body(Q, Pp, PD, PI, qg, r);
}

// ---------------------------------------------------------------------------
// Fused-pair fp32 GEMM host (512 threads = 2 teams x 256); blocks 0,1 = fps.
// act: 0 none, 1 gelu, 2 row-RMSNorm (requires N==128, resid) using scale.
// ---------------------------------------------------------------------------
__global__ __launch_bounds__(512) void gemm2_k(
    const float* __restrict__ A, const float* __restrict__ W,
    const float* __restrict__ bias, float* __restrict__ OUT,
    const float* __restrict__ resid, const float* __restrict__ scale,
    int nbx, int N, int K, int a_mode, int o_mode, int act,
    const float* __restrict__ P, float* __restrict__ MWS, float* __restrict__ LPWS,
    float* __restrict__ FPWS, float* __restrict__ OUTFP, int t0, int t1)
{
  if ((int)blockIdx.x < 2) {
    fps_slice(P, MWS, LPWS, FPWS, OUTFP, (int)blockIdx.x, t0, t1);
    return;
  }
  const int wid = (int)blockIdx.x - 2;
  __shared__ float As[2][16][132];
  __shared__ float Ws2[2][16][132];
  const int team = threadIdx.x >> 8;
  const int tid = threadIdx.x & 255;
  const int tx = tid & 15, ty = tid >> 4;
  const int bx = wid % nbx;
  const int byy = (wid / nbx) * 2 + team;
  float acc[8][8];
#pragma unroll
  for (int i = 0; i < 8; ++i)
#pragma unroll
    for (int j = 0; j < 8; ++j) acc[i][j] = 0.f;

  for (int k0 = 0; k0 < K; k0 += 16) {
#pragma unroll
    for (int rep = 0; rep < 2; ++rep) {
      int qq = tid + rep * 256;          // 0..511
      int m = qq >> 2, kq = qq & 3;      // A: 128 rows x 16k as float4
      int r = byy * 128 + m;
      int arow = (a_mode == 1) ? ((r & 8191) * 2 + (r >> 13)) : r;
      const float4 av = *(const float4*)(A + (long)arow * K + k0 + kq * 4);
      As[team][kq * 4 + 0][m] = av.x; As[team][kq * 4 + 1][m] = av.y;
      As[team][kq * 4 + 2][m] = av.z; As[team][kq * 4 + 3][m] = av.w;
      int kw = qq >> 5, nq = qq & 31;    // W: 16k x 128 cols
      const float4 wv = *(const float4*)(W + (long)(k0 + kw) * N + bx * 128 + nq * 4);
      *(float4*)&Ws2[team][kw][nq * 4] = wv;
    }
    __syncthreads();
#pragma unroll
    for (int kk = 0; kk < 16; ++kk) {
      float4 a0 = *(const float4*)&As[team][kk][ty * 8];
      float4 a1 = *(const float4*)&As[team][kk][ty * 8 + 4];
      float4 w0 = *(const float4*)&Ws2[team][kk][tx * 4];
      float4 w1 = *(const float4*)&Ws2[team][kk][64 + tx * 4];
      float am[8] = {a0.x, a0.y, a0.z, a0.w, a1.x, a1.y, a1.z, a1.w};
      float wn[8] = {w0.x, w0.y, w0.z, w0.w, w1.x, w1.y, w1.z, w1.w};
#pragma unroll
      for (int i = 0; i < 8; ++i)
#pragma unroll
        for (int j = 0; j < 8; ++j) acc[i][j] += am[i] * wn[j];
    }
    __syncthreads();
  }
  const int c0 = bx * 128 + tx * 4;
  const int c1 = c0 + 64;
  float4 ba = *(const float4*)(bias + c0);
  float4 bb = *(const float4*)(bias + c1);
  float4 sa = make_float4(1.f, 1.f, 1.f, 1.f), sb2 = sa;
  if (act == 2) {
    sa  = *(const float4*)(scale + c0);
    sb2 = *(const float4*)(scale + c1);
  }
#pragma unroll
  for (int i = 0; i < 8; ++i) {
    int r = byy * 128 + ty * 8 + i;
    int orow = (o_mode == 1) ? ((r & 8191) * 2 + (r >> 13))
             : (o_mode == 2) ? ((r & 1) * 8192 + (r >> 1)) : r;
    float o[8] = {acc[i][0] + ba.x, acc[i][1] + ba.y, acc[i][2] + ba.z, acc[i][3] + ba.w,
                  acc[i][4] + bb.x, acc[i][5] + bb.y, acc[i][6] + bb.z, acc[i][7] + bb.w};
    if (act == 1) {
#pragma unroll
      for (int j = 0; j < 8; ++j) o[j] = gelu_f(o[j]);
    }
    if (resid) {
      float4 r0 = *(const float4*)(resid + (long)orow * N + c0);
      float4 r1 = *(const float4*)(resid + (long)orow * N + c1);
      o[0] += r0.x; o[1] += r0.y; o[2] += r0.z; o[3] += r0.w;
      o[4] += r1.x; o[5] += r1.y; o[6] += r1.z; o[7] += r1.w;
    }
    if (act == 2) {
      // row RMS over the 128 cols held by the 16 same-ty threads
      float ss = 0.f;
#pragma unroll
      for (int j = 0; j < 8; ++j) ss += o[j] * o[j];
#pragma unroll
      for (int off = 1; off <= 8; off <<= 1) ss += __shfl_xor(ss, off);
      const float den = sqrtf(ss) / 11.313708498984761f + 1e-8f;
      float sc[8] = {sa.x, sa.y, sa.z, sa.w, sb2.x, sb2.y, sb2.z, sb2.w};
#pragma unroll
      for (int j = 0; j < 8; ++j) o[j] = sc[j] * (o[j] / den);
    }
    *(float4*)(OUT + (long)orow * N + c0) = make_float4(o[0], o[1], o[2], o[3]);
    *(float4*)(OUT + (long)orow * N + c1) = make_float4(o[4], o[5], o[6], o[7]);
  }
}

// ---------------------------------------------------------------------------
// Fused q,k,v GEMM host (one launch): 192 work blocks; sel = wid>>6 picks
// (Wq,qb) / (Wk,kb) / (Wv,vb); blocks 0,1 = fps. a_mode=1 row mapping.
// ---------------------------------------------------------------------------
__global__ __launch_bounds__(512) void gemmqkv_k(
    const float* __restrict__ A,
    const float* __restrict__ Wq, const float* __restrict__ bq, float* __restrict__ Oq,
    const float* __restrict__ Wk, const float* __restrict__ bk, float* __restrict__ Ok,
    const float* __restrict__ Wv, const float* __restrict__ bv, float* __restrict__ Ov,
    const float* __restrict__ P, float* __restrict__ MWS, float* __restrict__ LPWS,
    float* __restrict__ FPWS, float* __restrict__ OUTFP, int t0, int t1)
{
  if ((int)blockIdx.x < 2) {
    fps_slice(P, MWS, LPWS, FPWS, OUTFP, (int)blockIdx.x, t0, t1);
    return;
  }
  const int wid = (int)blockIdx.x - 2;   // 0..191
  const int sel = wid >> 6;              // 0=q 1=k 2=v
  const float* W = (sel == 0) ? Wq : (sel == 1) ? Wk : Wv;
  const float* bias = (sel == 0) ? bq : (sel == 1) ? bk : bv;
  float* OUT = (sel == 0) ? Oq : (sel == 1) ? Ok : Ov;
  __shared__ float As[2][16][132];
  __shared__ float Ws2[2][16][132];
  const int team = threadIdx.x >> 8;
  const int tid = threadIdx.x & 255;
  const int tx = tid & 15, ty = tid >> 4;
  const int byy = (wid & 63) * 2 + team;
  float acc[8][8];
#pragma unroll
  for (int i = 0; i < 8; ++i)
#pragma unroll
    for (int j = 0; j < 8; ++j) acc[i][j] = 0.f;

  for (int k0 = 0; k0 < 128; k0 += 16) {
#pragma unroll
    for (int rep = 0; rep < 2; ++rep) {
      int qq = tid + rep * 256;
      int m = qq >> 2, kq = qq & 3;
      int r = byy * 128 + m;
      int arow = (r & 8191) * 2 + (r >> 13);
      const float4 av = *(const float4*)(A + (long)arow * 128 + k0 + kq * 4);
      As[team][kq * 4 + 0][m] = av.x; As[team][kq * 4 + 1][m] = av.y;
      As[team][kq * 4 + 2][m] = av.z; As[team][kq * 4 + 3][m] = av.w;
      int kw = qq >> 5, nq = qq & 31;
      const float4 wv = *(const float4*)(W + (long)(k0 + kw) * 128 + nq * 4);
      *(float4*)&Ws2[team][kw][nq * 4] = wv;
    }
    __syncthreads();
#pragma unroll
    for (int kk = 0; kk < 16; ++kk) {
      float4 a0 = *(const float4*)&As[team][kk][ty * 8];
      float4 a1 = *(const float4*)&As[team][kk][ty * 8 + 4];
      float4 w0 = *(const float4*)&Ws2[team][kk][tx * 4];
      float4 w1 = *(const float4*)&Ws2[team][kk][64 + tx * 4];
      float am[8] = {a0.x, a0.y, a0.z, a0.w, a1.x, a1.y, a1.z, a1.w};
      float wn[8] = {w0.x, w0.y, w0.z, w0.w, w1.x, w1.y, w1.z, w1.w};
#pragma unroll
      for (int i = 0; i < 8; ++i)
#pragma unroll
        for (int j = 0; j < 8; ++j) acc[i][j] += am[i] * wn[j];
    }
    __syncthreads();
  }
  const int c0 = tx * 4;
  const int c1 = c0 + 64;
  float4 ba = *(const float4*)(bias + c0);
  float4 bb = *(const float4*)(bias + c1);
#pragma unroll
  for (int i = 0; i < 8; ++i) {
    int orow = byy * 128 + ty * 8 + i;
    float o[8] = {acc[i][0] + ba.x, acc[i][1] + ba.y, acc[i][2] + ba.z, acc[i][3] + ba.w,
                  acc[i][4] + bb.x, acc[i][5] + bb.y, acc[i][6] + bb.z, acc[i][7] + bb.w};
    *(float4*)(OUT + (long)orow * 128 + c0) = make_float4(o[0], o[1], o[2], o[3]);
    *(float4*)(OUT + (long)orow * 128 + c1) = make_float4(o[4], o[5], o[6], o[7]);
  }
}

// ---------------------------------------------------------------------------
// Partial KNN1 host (512 thr); blocks 0,1 = fps. 128 work blocks:
// wid = bid-2; qg = wid>>2 (32 groups of 512 queries); r = wid&3 (cand range).
// ---------------------------------------------------------------------------
__global__ __launch_bounds__(512) void knn1p_k(
    const float* __restrict__ Pp, float* __restrict__ PD, int* __restrict__ PI,
    const float* __restrict__ P, float* __restrict__ MWS, float* __restrict__ LPWS,
    float* __restrict__ FPWS, float* __restrict__ OUTFP, int t0, int t1)
{
  if ((int)blockIdx.x < 2) {
    fps_slice(P, MWS, LPWS, FPWS, OUTFP, (int)blockIdx.x, t0, t1);
    return;
  }
  const int wid = (int)blockIdx.x - 2;   // 0..127
  const int qg = wid >> 2;               // 0..31
  const int r = wid & 3;
  const int b = qg >> 4;                 // 16 groups per batch
  const int m = (qg & 15) * 512 + threadIdx.x;
  __shared__ float4 shp[512];
  const float qx = Pp[(b * N_PTS + m) * 3 + 0];
  const float qy = Pp[(b * N_PTS + m) * 3 + 1];
  const float qz = Pp[(b * N_PTS + m) * 3 + 2];
  const float sqq = __fadd_rn(__fadd_rn(__fmul_rn(qx, qx), __fmul_rn(qy, qy)), __fmul_rn(qz, qz));
  float dist[8]; int idq[8];
#pragma unroll
  for (int j = 0; j < 8; ++j) { dist[j] = INFINITY; idq[j] = 0; }
  const int cb = r * 2048;
  for (int tt = 0; tt < 2048; tt += 512) {
    __syncthreads();
    {
      int l = threadIdx.x;
      float x = Pp[(b * N_PTS + cb + tt + l) * 3 + 0];
      float y = Pp[(b * N_PTS + cb + tt + l) * 3 + 1];
      float z = Pp[(b * N_PTS + cb + tt + l) * 3 + 2];
      float s = __fadd_rn(__fadd_rn(__fmul_rn(x, x), __fmul_rn(y, y)), __fmul_rn(z, z));
      shp[l] = make_float4(x, y, z, s);
    }
    __syncthreads();
    for (int c = 0; c < 512; c += 4) {
      float4 p0 = shp[c + 0];
      float4 p1 = shp[c + 1];
      float4 p2 = shp[c + 2];
      float4 p3 = shp[c + 3];
      float d0 = __fsub_rn(__fadd_rn(sqq, p0.w), __fmul_rn(2.0f,
                 __fadd_rn(__fadd_rn(__fmul_rn(qx, p0.x), __fmul_rn(qy, p0.y)), __fmul_rn(qz, p0.z))));
      float d1 = __fsub_rn(__fadd_rn(sqq, p1.w), __fmul_rn(2.0f,
                 __fadd_rn(__fadd_rn(__fmul_rn(qx, p1.x), __fmul_rn(qy, p1.y)), __fmul_rn(qz, p1.z))));
      float d2 = __fsub_rn(__fadd_rn(sqq, p2.w), __fmul_rn(2.0f,
                 __fadd_rn(__fadd_rn(__fmul_rn(qx, p2.x), __fmul_rn(qy, p2.y)), __fmul_rn(qz, p2.z))));
      float d3 = __fsub_rn(__fadd_rn(sqq, p3.w), __fmul_rn(2.0f,
                 __fadd_rn(__fadd_rn(__fmul_rn(qx, p3.x), __fmul_rn(qy, p3.y)), __fmul_rn(qz, p3.z))));
      float mn = fminf(fminf(d0, d1), fminf(d2, d3));
      if (mn < dist[7]) {
        knn_insert(dist, idq, d0, cb + tt + c + 0);
        knn_insert(dist, idq, d1, cb + tt + c + 1);
        knn_insert(dist, idq, d2, cb + tt + c + 2);
        knn_insert(dist, idq, d3, cb + tt + c + 3);
      }
    }
  }
  const long ob = ((long)(b * N_PTS + m) * 4 + r) * 8;
#pragma unroll
  for (int j = 0; j < 8; ++j) { PD[ob + j] = dist[j]; PI[ob + j] = idq[j]; }
}

// ---------------------------------------------------------------------------
// Fused neighbor attention, 512-thr host; blocks 0,1 = fps.
// Merges the 4 knn1 partial lists inline per wave.
// ---------------------------------------------------------------------------
__global__ __launch_bounds__(512) void attn_k(
    const float* __restrict__ Qb, const float* __restrict__ Kb, const float* __restrict__ Vb,
    const float* __restrict__ Pp,
    const float* __restrict__ PD1, const int* __restrict__ PI1,
    const float* __restrict__ Wpe1, const float* __restrict__ bpe1,
    const float* __restrict__ Wpe2, const float* __restrict__ bpe2,
    const float* __restrict__ Wg, const float* __restrict__ bg,
    float* __restrict__ RES,
    const float* __restrict__ P, float* __restrict__ MWS, float* __restrict__ LPWS,
    float* __restrict__ FPWS, float* __restrict__ OUTFP, int t0, int t1)
{
  if ((int)blockIdx.x < 2) {
    fps_slice(P, MWS, LPWS, FPWS, OUTFP, (int)blockIdx.x, t0, t1);
    return;
  }
  __shared__ float sbuf[8][1024];
  const int tid = threadIdx.x;
  const int w = tid >> 6, lane = tid & 63;
  const int g = ((int)blockIdx.x - 2) * 8 + w;   // 0..16383 : b*8192+n
  const int b = g >> 13, n = g & 8191;
  const int j0 = lane * 2;
  float* sb = sbuf[w];
  const float2 qv = *(const float2*)(Qb + (long)g * 128 + j0);
  // inline merge of 4 partial top-8 lists (wave-uniform, broadcast loads)
  float mdist[8]; int nb[8];
#pragma unroll
  for (int j = 0; j < 8; ++j) { mdist[j] = INFINITY; nb[j] = 0; }
#pragma unroll
  for (int r = 0; r < 4; ++r) {
    const long ob = ((long)g * 4 + r) * 8;
#pragma unroll
    for (int j = 0; j < 8; ++j) knn_insert(mdist, nb, PD1[ob + j], PI1[ob + j]);
  }
  const float p0 = Pp[(b * N_PTS + n) * 3 + 0];
  const float p1 = Pp[(b * N_PTS + n) * 3 + 1];
  const float p2 = Pp[(b * N_PTS + n) * 3 + 2];
  // phase A: h1 = gelu(rel @ Wpe1 + bpe1) -> LDS
  const float2 w1a = *(const float2*)(Wpe1 + j0);
  const float2 w1b = *(const float2*)(Wpe1 + 128 + j0);
  const float2 w1c = *(const float2*)(Wpe1 + 256 + j0);
  const float2 b1 = *(const float2*)(bpe1 + j0);
#pragma unroll
  for (int kk = 0; kk < 8; ++kk) {
    const float* pn = Pp + (long)(b * N_PTS + nb[kk]) * 3;
    float r0 = p0 - pn[0], r1 = p1 - pn[1], r2 = p2 - pn[2];
    float h0 = r0 * w1a.x + r1 * w1b.x + r2 * w1c.x + b1.x;
    float h1 = r0 * w1a.y + r1 * w1b.y + r2 * w1c.y + b1.y;
    sb[kk * 128 + j0]     = gelu_f(h0);
    sb[kk * 128 + j0 + 1] = gelu_f(h1);
  }
  __syncthreads();
  // phase B: pe = h1 @ Wpe2
  float2 pe[8];
#pragma unroll
  for (int kk = 0; kk < 8; ++kk) pe[kk] = make_float2(0.f, 0.f);
  for (int i = 0; i < 128; i += 2) {
    float2 wa = *(const float2*)(Wpe2 + (long)i * 128 + j0);
    float2 wb = *(const float2*)(Wpe2 + (long)(i + 1) * 128 + j0);
#pragma unroll
    for (int kk = 0; kk < 8; ++kk) {
      float2 hh = *(const float2*)&sb[kk * 128 + i];
      pe[kk].x += hh.x * wa.x + hh.y * wb.x;
      pe[kk].y += hh.x * wa.y + hh.y * wb.y;
    }
  }
  const float2 b2v = *(const float2*)(bpe2 + j0);
  __syncthreads();
  // t = q - k_nb + pe  -> LDS (reuse buffer)
#pragma unroll
  for (int kk = 0; kk < 8; ++kk) {
    pe[kk].x += b2v.x; pe[kk].y += b2v.y;
    const float2 kv = *(const float2*)(Kb + (long)(b * N_PTS + nb[kk]) * 128 + j0);
    sb[kk * 128 + j0]     = qv.x - kv.x + pe[kk].x;
    sb[kk * 128 + j0 + 1] = qv.y - kv.y + pe[kk].y;
  }
  __syncthreads();
  // phase C: a = t @ Wg
  float2 av[8];
#pragma unroll
  for (int kk = 0; kk < 8; ++kk) av[kk] = make_float2(0.f, 0.f);
  for (int i = 0; i < 128; i += 2) {
    float2 wa = *(const float2*)(Wg + (long)i * 128 + j0);
    float2 wb = *(const float2*)(Wg + (long)(i + 1) * 128 + j0);
#pragma unroll
    for (int kk = 0; kk < 8; ++kk) {
      float2 tt = *(const float2*)&sb[kk * 128 + i];
      av[kk].x += tt.x * wa.x + tt.y * wb.x;
      av[kk].y += tt.x * wa.y + tt.y * wb.y;
    }
  }
  const float2 bgv = *(const float2*)(bg + j0);
  float2 resv = make_float2(0.f, 0.f);
  const float sd = 11.313708498984761f;   // sqrt(128)
#pragma unroll
  for (int kk = 0; kk < 8; ++kk) {
    float l0 = (av[kk].x + bgv.x) / sd;
    float l1 = (av[kk].y + bgv.y) / sd;
    float mx = fmaxf(l0, l1);
#pragma unroll
    for (int off = 32; off >= 1; off >>= 1) mx = fmaxf(mx, __shfl_xor(mx, off));
    float e0 = expf(l0 - mx), e1 = expf(l1 - mx);
    float sm = e0 + e1;
#pragma unroll
    for (int off = 32; off >= 1; off >>= 1) sm += __shfl_xor(sm, off);
    const float2 vv = *(const float2*)(Vb + (long)(b * N_PTS + nb[kk]) * 128 + j0);
    resv.x += (e0 / sm) * (vv.x + pe[kk].x);
    resv.y += (e1 / sm) * (vv.y + pe[kk].y);
  }
  *(float2*)(RES + (long)g * 128 + j0) = resv;
}

// ---------------------------------------------------------------------------
// PointPool with inline merge of the 8 knn2 partial lists per output point.
// ---------------------------------------------------------------------------
__global__ __launch_bounds__(256) void pool_k(
    const float* __restrict__ X3, const float* __restrict__ FPWS,
    const float* __restrict__ PD2, const int* __restrict__ PI2,
    const float* __restrict__ Wp, float* __restrict__ OUT)
{
  __shared__ float sh[8][256];
  __shared__ float fp3[3];
  const int bm = blockIdx.x;           // b*2048 + m
  const int b = bm >> 11;
  const int m = bm & 2047;
  const int tid = threadIdx.x;
  // inline merge (block-uniform, broadcast loads)
  float mdist[8]; int kidx[8];
#pragma unroll
  for (int j = 0; j < 8; ++j) { mdist[j] = INFINITY; kidx[j] = 0; }
#pragma unroll
  for (int r = 0; r < 8; ++r) {
    const long ob = ((long)bm * 8 + r) * 8;
#pragma unroll
    for (int j = 0; j < 8; ++j) knn_insert(mdist, kidx, PD2[ob + j], PI2[ob + j]);
  }
#pragma unroll
  for (int kk = 0; kk < 8; ++kk) {
    sh[kk][tid] = X3[(long)(b * N_PTS + kidx[kk]) * 256 + tid];
  }
  if (tid < 3) fp3[tid] = FPWS[bm * 3 + tid];
  __syncthreads();
  float base = fp3[0] * Wp[tid] + fp3[1] * Wp[256 + tid] + fp3[2] * Wp[512 + tid];
  float acc[8];
#pragma unroll
  for (int kk = 0; kk < 8; ++kk) acc[kk] = base;
  for (int i = 0; i < 256; i += 2) {
    float w0 = Wp[(3 + i) * 256 + tid];
    float w1 = Wp[(4 + i) * 256 + tid];
#pragma unroll
    for (int kk = 0; kk < 8; ++kk) {
      float2 hh = *(const float2*)&sh[kk][i];
      acc[kk] += hh.x * w0 + hh.y * w1;
    }
  }
  float mx = -INFINITY;
#pragma unroll
  for (int kk = 0; kk < 8; ++kk) {
    float a = acc[kk];
    a = (a >= 0.f) ? a : 0.01f * a;      // LeakyReLU(0.01)
    mx = fmaxf(mx, a);
  }
  OUT[(long)(m * 2 + b) * 256 + tid] = mx;   // (n_out, B, 2D)
}

// ---------------------------------------------------------------------------
extern "C" void kernel_launch(void* const* d_in, const int* in_sizes, int n_in,
                              void* d_out, int out_size, void* d_ws, size_t ws_size,
                              hipStream_t stream)
{
  (void)in_sizes; (void)n_in; (void)out_size; (void)ws_size;
  const float* x    = (const float*)d_in[0];
  const float* ppos = (const float*)d_in[1];
  const float* Wq = (const float*)d_in[2];   const float* bq = (const float*)d_in[3];
  const float* Wk = (const float*)d_in[4];   const float* bk = (const float*)d_in[5];
  const float* Wv = (const float*)d_in[6];   const float* bv = (const float*)d_in[7];
  const float* Wpe1 = (const float*)d_in[8]; const float* bpe1 = (const float*)d_in[9];
  const float* Wpe2 = (const float*)d_in[10];const float* bpe2 = (const float*)d_in[11];
  const float* Wg = (const float*)d_in[12];  const float* bg = (const float*)d_in[13];
  const float* Wo = (const float*)d_in[14];  const float* bo = (const float*)d_in[15];
  const float* scale = (const float*)d_in[16];
  const float* Wf1 = (const float*)d_in[17]; const float* bf1 = (const float*)d_in[18];
  const float* Wf2 = (const float*)d_in[19]; const float* bf2 = (const float*)d_in[20];
  const float* Wpool = (const float*)d_in[21];
  float* out = (float*)d_out;
  char* ws = (char*)d_ws;

  // workspace layout (peak ~49 MB, aliased):
  float* qb   = (float*)(ws);                                   // 8 MB (B,N,128)
  float* kb   = (float*)(ws + (size_t)8 * 1024 * 1024);         // 8 MB
  float* vb   = (float*)(ws + (size_t)16 * 1024 * 1024);        // 8 MB
  float* res  = (float*)(ws + (size_t)24 * 1024 * 1024);        // 8 MB
  float* x2   = (float*)(ws + (size_t)32 * 1024 * 1024);        // 8 MB (N,B,128)
  float* hbuf = (float*)(ws);                                   // 32 MB, aliases qb..res
  float* x3   = (float*)(ws + (size_t)32 * 1024 * 1024);        // 16 MB (B,N,256), aliases x2
  // knn1 partials in the x2 slot (consumed by attn BEFORE Wo writes x2)
  float* PD1  = (float*)(ws + (size_t)32 * 1024 * 1024);        // 2 MB
  int*   PI1  = (int*)  (ws + (size_t)34 * 1024 * 1024);        // 2 MB
  // knn2 partials in the hbuf slot (dead after ffn2; written in fin and later)
  float* PD2  = (float*)(ws);                                   // 1 MB
  int*   PI2  = (int*)  (ws + (size_t)1 * 1024 * 1024);         // 1 MB
  char*  tail = ws + (size_t)48 * 1024 * 1024;
  float* fpws = (float*)(tail);                       // 64 KB slot (48 used)
  float* MWS  = (float*)(tail + 65536);               // 64 KB fps mind state
  float* LPWS = (float*)(tail + 131072);              // 4 KB fps lp state

  // fps spans (sum = 2048): qkv 230, knn1p 270, attn 540, Wo+rms 110,
  // ffn1 250, ffn2 130 -> hosted 1530; fin 518 (SLICE_MAX=560 covers all).
  gemmqkv_k<<<dim3(194), dim3(512), 0, stream>>>(x, Wq, bq, qb, Wk, bk, kb, Wv, bv, vb,
                                                 ppos, MWS, LPWS, fpws, out, 0, 230);
  knn1p_k<<<dim3(130), dim3(512), 0, stream>>>(ppos, PD1, PI1,
                                               ppos, MWS, LPWS, fpws, out, 230, 500);
  attn_k<<<dim3(2050), dim3(512), 0, stream>>>(qb, kb, vb, ppos, PD1, PI1,
                                               Wpe1, bpe1, Wpe2, bpe2, Wg, bg, res,
                                               ppos, MWS, LPWS, fpws, out, 500, 1040);
  // Wo + residual + fused RMSNorm -> x2
  gemm2_k<<<dim3(66), dim3(512), 0, stream>>>(res, Wo, bo, x2, x, scale, 1, 128, 128, 0, 1, 2,
                                              ppos, MWS, LPWS, fpws, out, 1040, 1150);
  gemm2_k<<<dim3(258), dim3(512), 0, stream>>>(x2, Wf1, bf1, hbuf, nullptr, nullptr, 4, 512, 128, 0, 0, 1,
                                               ppos, MWS, LPWS, fpws, out, 1150, 1400);
  gemm2_k<<<dim3(130), dim3(512), 0, stream>>>(hbuf, Wf2, bf2, x3, nullptr, nullptr, 2, 256, 512, 0, 2, 0,
                                               ppos, MWS, LPWS, fpws, out, 1400, 1530);
  // fin: fps 1530->2048 on blocks 0,1 + knn2 partials for queries < 512/batch
  fps_fin<<<dim3(18), dim3(512), 0, stream>>>(ppos, MWS, LPWS, fpws, out, PD2, PI2, 1530, 2048);
  // remaining knn2 partials (queries 512..2047 per batch)
  knn2pb_k<<<dim3(48), dim3(512), 0, stream>>>(fpws, ppos, PD2, PI2);
  // pooling (inline merge of partials) -> output 0
  pool_k<<<dim3(4096), dim3(256), 0, stream>>>(x3, fpws, PD2, PI2, Wpool, out);
}